// Round 3
// baseline (1035.182 us; speedup 1.0000x reference)
//
#include <hip/hip_runtime.h>
#include <hip/hip_bf16.h>
#include <math.h>

// ---------------- problem constants (from setup_inputs) ----------------
#define DM    768           // model dim
#define NH    12            // heads
#define HD    64            // head dim
#define BB    8             // batch
#define FF    8             // frames
#define NP    196           // spatial positions
#define NT    1569          // 1 + FF*NP tokens
#define MROWS 12552         // BB*NT
#define MPAD  12672         // buffer row padding (allocation only)
#define MT    50            // ceil(MROWS/256) row tiles for 256^2 GEMM
#define QKVN  2304          // 3*DM
#define FCN   3072          // 4*DM

typedef short s16;          // bf16 stored as raw 16-bit
typedef __attribute__((ext_vector_type(8))) short short8;
typedef __attribute__((ext_vector_type(4))) float floatx4;

__device__ __forceinline__ float bf2f(s16 s) {
  union { unsigned u; float f; } x;
  x.u = ((unsigned)(unsigned short)s) << 16;
  return x.f;
}
__device__ __forceinline__ s16 f2bf(float f) {
  __hip_bfloat16 h = __float2bfloat16(f);
  s16 r;
  __builtin_memcpy(&r, &h, sizeof(r));
  return r;
}
__device__ __forceinline__ void gload16(const void* g, void* l) {
  __builtin_amdgcn_global_load_lds(
      (__attribute__((address_space(1))) void*)g,
      (__attribute__((address_space(3))) void*)l, 16, 0, 0);
}

// ---------------- weight transpose + fp32->bf16 convert ----------------
__global__ void wtrans(const float* __restrict__ W, s16* __restrict__ Wt,
                       int K, int Nn) {
  __shared__ float t[32][33];
  int n0 = blockIdx.x * 32, k0 = blockIdx.y * 32;
  int tx = threadIdx.x, ty = threadIdx.y;   // (32,8)
#pragma unroll
  for (int i = 0; i < 4; ++i)
    t[ty + 8*i][tx] = W[(size_t)(k0 + ty + 8*i) * Nn + n0 + tx];
  __syncthreads();
#pragma unroll
  for (int i = 0; i < 4; ++i)
    Wt[(size_t)(n0 + ty + 8*i) * K + k0 + tx] = f2bf(t[tx][ty + 8*i]);
}

// ---------------- LayerNorm fp32 -> bf16 ----------------
__global__ __launch_bounds__(256) void ln_k(const float* __restrict__ in,
                                            const float* __restrict__ g,
                                            const float* __restrict__ b,
                                            s16* __restrict__ out) {
  __shared__ float red[8];
  int row = blockIdx.x;
  int tid = threadIdx.x;
  const float* rp = in + (size_t)row * DM;
  float v0 = rp[tid], v1 = rp[tid + 256], v2 = rp[tid + 512];
  float s = v0 + v1 + v2;
#pragma unroll
  for (int o = 32; o; o >>= 1) s += __shfl_down(s, o);
  if ((tid & 63) == 0) red[tid >> 6] = s;
  __syncthreads();
  float mean = (red[0] + red[1] + red[2] + red[3]) * (1.0f / DM);
  __syncthreads();
  float d0 = v0 - mean, d1 = v1 - mean, d2 = v2 - mean;
  float q = d0*d0 + d1*d1 + d2*d2;
#pragma unroll
  for (int o = 32; o; o >>= 1) q += __shfl_down(q, o);
  if ((tid & 63) == 0) red[tid >> 6] = q;
  __syncthreads();
  float var = (red[0] + red[1] + red[2] + red[3]) * (1.0f / DM);
  float rs = rsqrtf(var + 1e-5f);
  s16* op = out + (size_t)row * DM;
  op[tid      ] = f2bf(d0 * rs * g[tid      ] + b[tid      ]);
  op[tid + 256] = f2bf(d1 * rs * g[tid + 256] + b[tid + 256]);
  op[tid + 512] = f2bf(d2 * rs * g[tid + 512] + b[tid + 512]);
}

// ---------------- 256x256 8-phase deep-pipelined bf16 MFMA GEMM ----------------
// A(M,K) row-major bf16, Bt(N,K) row-major bf16 (k-contiguous), C = A*Bt^T.
// 512 threads = 8 waves (2 Mrows x 4 Ncols), per-wave C = 128x64 = 8x4 frags.
// BK=64, double-buffered 128 KiB LDS. Per K-tile: 4 phases, each
// {ds_read frags; stage half-tile; s_barrier; setprio+16 MFMA; s_barrier}.
// Staging: A(kt+1)->other buf (ph0/1), B(kt+2)->current buf B region (ph2/3;
// free after ph0 since B frags are consumed before ph0's closing barrier).
// One counted s_waitcnt vmcnt(4) per K-tile (4 newest loads stay in flight).
// T2 st_16x32 swizzle: linear LDS dest (gload_lds), inverse-swizzled global
// source col (bit (tid>>5)&1), swizzled ds_read col (bit (lane>>2)&1).
// EPI: 0 = bias->bf16 ; 1 = bias+GELU->bf16 ; 2 = bias+resid->fp32
template<int EPI>
__global__ __launch_bounds__(512, 2) void gemm256(const s16* __restrict__ A,
                                                  const s16* __restrict__ Bt,
                                                  const float* __restrict__ bias,
                                                  const float* __restrict__ resid,
                                                  void* __restrict__ out,
                                                  int K, int Nn, int xt) {
  __shared__ s16 As[2][256 * 64];
  __shared__ s16 Bs[2][256 * 64];
  // bijective XCD swizzle (m204): contiguous wgid chunk per XCD
  const int nwg = gridDim.x, orig = blockIdx.x;
  const int qq = nwg >> 3, rr = nwg & 7, xcd = orig & 7, lid = orig >> 3;
  const int wgid = (xcd < rr ? xcd * (qq + 1) : rr * (qq + 1) + (xcd - rr) * qq) + lid;
  const int bx = wgid % xt, by = wgid / xt;
  const int row0 = by * 256, col0 = bx * 256;
  const int tid = threadIdx.x, lane = tid & 63, w = tid >> 6;
  const int wr = w >> 2, wc = w & 3;
  const int lr = lane & 15, hi = lane >> 4;
  const int nt = K >> 6;

  // staging addressing: thread covers row srow of a 64-row slab, 16B chunk (lane&7)
  const int colg = ((lane & 7) * 8) ^ (((lane >> 5) & 1) << 4);  // inverse-swizzled src col
  const int srow = tid >> 3;                                     // 0..63
  const int ldsc = (lane & 7) * 8;                               // linear LDS col (elems)

#define STAGE_A(half, k0s)                                                        \
  {                                                                               \
    _Pragma("unroll")                                                             \
    for (int i = 0; i < 2; ++i) {                                                 \
      int rl = (half) * 128 + i * 64 + srow;                                      \
      int rg = row0 + rl; if (rg > MROWS - 1) rg = MROWS - 1;                     \
      gload16(A + (size_t)rg * K + (k0s) + colg, Adst + rl * 64 + ldsc);          \
    }                                                                             \
  }
#define STAGE_B(half, k0s, Bd)                                                    \
  {                                                                               \
    _Pragma("unroll")                                                             \
    for (int i = 0; i < 2; ++i) {                                                 \
      int rl = (half) * 128 + i * 64 + srow;                                      \
      gload16(Bt + (size_t)(col0 + rl) * K + (k0s) + colg, (Bd) + rl * 64 + ldsc);\
    }                                                                             \
  }

  // ---- prologue: A(0),B(0) -> buf0 ; B(1) -> buf1 ; wait first 8 of 12 ----
  {
    s16* Adst = As[0];
    STAGE_A(0, 0) STAGE_A(1, 0)
    STAGE_B(0, 0, Bs[0]) STAGE_B(1, 0, Bs[0])
    int k1 = 64;                       // nt >= 2 always here
    STAGE_B(0, k1, Bs[1]) STAGE_B(1, k1, Bs[1])
  }
  asm volatile("s_waitcnt vmcnt(4)" ::: "memory");
  __builtin_amdgcn_s_barrier();

  floatx4 acc[8][4] = {};
  const int rdswz = ((lr >> 2) & 1) << 4;    // read-side swizzle (elems)

  for (int kt = 0; kt < nt; ++kt) {
    const int bb = kt & 1;
    const s16* Ab = As[bb];
    const s16* Bb = Bs[bb];
    s16* Adst = As[bb ^ 1];
    s16* Bdst = Bs[bb];                      // B region of current buf: free after ph0
    const int ka  = ((kt + 1) < nt ? (kt + 1) : 0) * 64;
    const int kb2 = ((kt + 2) < nt ? (kt + 2) : (kt + 2 - nt)) * 64;

    // B frags for the whole K-tile (consumed before ph0's closing barrier)
    short8 bq[4][2];
#pragma unroll
    for (int ni = 0; ni < 4; ++ni)
#pragma unroll
      for (int ks = 0; ks < 2; ++ks)
        bq[ni][ks] = *reinterpret_cast<const short8*>(
            Bb + (wc * 64 + ni * 16 + lr) * 64 + ((ks * 32 + hi * 8) ^ rdswz));

#pragma unroll
    for (int ph = 0; ph < 4; ++ph) {
      short8 aq[2][2];
#pragma unroll
      for (int m = 0; m < 2; ++m)
#pragma unroll
        for (int ks = 0; ks < 2; ++ks)
          aq[m][ks] = *reinterpret_cast<const short8*>(
              Ab + (wr * 128 + (ph * 2 + m) * 16 + lr) * 64 + ((ks * 32 + hi * 8) ^ rdswz));
      if (ph == 0)      STAGE_A(0, ka)
      else if (ph == 1) STAGE_A(1, ka)
      else if (ph == 2) STAGE_B(0, kb2, Bdst)
      else              STAGE_B(1, kb2, Bdst)
      __builtin_amdgcn_s_barrier();
      __builtin_amdgcn_s_setprio(1);
#pragma unroll
      for (int ni = 0; ni < 4; ++ni)
#pragma unroll
        for (int m = 0; m < 2; ++m) {
          acc[ph * 2 + m][ni] = __builtin_amdgcn_mfma_f32_16x16x32_bf16(
              aq[m][0], bq[ni][0], acc[ph * 2 + m][ni], 0, 0, 0);
          acc[ph * 2 + m][ni] = __builtin_amdgcn_mfma_f32_16x16x32_bf16(
              aq[m][1], bq[ni][1], acc[ph * 2 + m][ni], 0, 0, 0);
        }
      __builtin_amdgcn_s_setprio(0);
      if (ph == 3) asm volatile("s_waitcnt vmcnt(4)" ::: "memory");
      __builtin_amdgcn_s_barrier();
    }
  }
#undef STAGE_A
#undef STAGE_B

  // ---- epilogue: C row = row0+wr*128+mi*16+(lane>>4)*4+j, col = col0+wc*64+ni*16+(lane&15)
#pragma unroll
  for (int mi = 0; mi < 8; ++mi) {
#pragma unroll
    for (int j = 0; j < 4; ++j) {
      int r = row0 + wr * 128 + mi * 16 + hi * 4 + j;
      if (r >= MROWS) continue;
#pragma unroll
      for (int ni = 0; ni < 4; ++ni) {
        int c = col0 + wc * 64 + ni * 16 + lr;
        float v = acc[mi][ni][j] + bias[c];
        size_t idx = (size_t)r * Nn + c;
        if (EPI == 0) {
          ((s16*)out)[idx] = f2bf(v);
        } else if (EPI == 1) {
          float ge = 0.5f * v * (1.0f + erff(v * 0.70710678118654752f));
          ((s16*)out)[idx] = f2bf(ge);
        } else {
          ((float*)out)[idx] = resid[idx] + v;
        }
      }
    }
  }
}

// ---------------- cls-token attention: 1 query over all NT keys ----------------
__global__ __launch_bounds__(256) void cls_attn(const s16* __restrict__ qkv,
                                                s16* __restrict__ aout) {
  __shared__ float qs[64];
  __shared__ float sc[NT];
  __shared__ float pacc[4][64];
  __shared__ float red[8];
  int bh = blockIdx.x; int b = bh / NH, h = bh % NH;
  int tid = threadIdx.x;
  if (tid < 64) qs[tid] = 0.125f * bf2f(qkv[(size_t)(b*NT) * QKVN + h*HD + tid]);
  __syncthreads();
  for (int t = tid; t < NT; t += 256) {
    const s16* kp = qkv + (size_t)(b*NT + t) * QKVN + DM + h*HD;
    float dot = 0.f;
#pragma unroll
    for (int d8 = 0; d8 < 8; ++d8) {
      short8 kv = *reinterpret_cast<const short8*>(kp + d8*8);
#pragma unroll
      for (int j = 0; j < 8; ++j) dot += qs[d8*8 + j] * bf2f(kv[j]);
    }
    sc[t] = dot;
  }
  __syncthreads();
  float m = -1e30f;
  for (int t = tid; t < NT; t += 256) m = fmaxf(m, sc[t]);
#pragma unroll
  for (int o = 32; o; o >>= 1) m = fmaxf(m, __shfl_xor(m, o));
  if ((tid & 63) == 0) red[tid >> 6] = m;
  __syncthreads();
  m = fmaxf(fmaxf(red[0], red[1]), fmaxf(red[2], red[3]));
  __syncthreads();
  float s = 0.f;
  for (int t = tid; t < NT; t += 256) { float e = expf(sc[t] - m); sc[t] = e; s += e; }
#pragma unroll
  for (int o = 32; o; o >>= 1) s += __shfl_xor(s, o);
  if ((tid & 63) == 0) red[tid >> 6] = s;
  __syncthreads();
  float inv = 1.0f / (red[0] + red[1] + red[2] + red[3]);
  int d = tid & 63, part = tid >> 6;
  float a = 0.f;
  for (int t = part; t < NT; t += 4)
    a += sc[t] * bf2f(qkv[(size_t)(b*NT + t) * QKVN + 2*DM + h*HD + d]);
  pacc[part][d] = a;
  __syncthreads();
  if (tid < 64) {
    float o = (pacc[0][tid] + pacc[1][tid] + pacc[2][tid] + pacc[3][tid]) * inv;
    aout[(size_t)(b*NT) * DM + h*HD + tid] = f2bf(o);
  }
}

// ---------------- time attention: group=(b,h,p), 8 queries x 9 keys ----------------
__global__ __launch_bounds__(256) void time_attn(const s16* __restrict__ qkv,
                                                 s16* __restrict__ aout) {
  int g = blockIdx.x * 4 + (threadIdx.x >> 6);
  int lane = threadIdx.x & 63;
  int p = g % NP; int bh = g / NP; int b = bh / NH, h = bh % NH;
  int qi = lane >> 3;
  int dc = (lane & 7) * 8;
  int tokq = 1 + qi*NP + p;
  short8 qv = *reinterpret_cast<const short8*>(qkv + (size_t)(b*NT + tokq)*QKVN + h*HD + dc);
  float qf[8];
#pragma unroll
  for (int j = 0; j < 8; ++j) qf[j] = 0.125f * bf2f(qv[j]);
  float s[9];
#pragma unroll
  for (int kj = 0; kj < 9; ++kj) {
    int tok = (kj == 0) ? 0 : (1 + (kj - 1)*NP + p);
    short8 kv = *reinterpret_cast<const short8*>(qkv + (size_t)(b*NT + tok)*QKVN + DM + h*HD + dc);
    float d = 0.f;
#pragma unroll
    for (int j = 0; j < 8; ++j) d += qf[j] * bf2f(kv[j]);
    d += __shfl_xor(d, 1); d += __shfl_xor(d, 2); d += __shfl_xor(d, 4);
    s[kj] = d;
  }
  float m = s[0];
#pragma unroll
  for (int kj = 1; kj < 9; ++kj) m = fmaxf(m, s[kj]);
  float sum = 0.f;
#pragma unroll
  for (int kj = 0; kj < 9; ++kj) { s[kj] = expf(s[kj] - m); sum += s[kj]; }
  float inv = 1.0f / sum;
  float o[8] = {0,0,0,0,0,0,0,0};
#pragma unroll
  for (int kj = 0; kj < 9; ++kj) {
    int tok = (kj == 0) ? 0 : (1 + (kj - 1)*NP + p);
    short8 vv = *reinterpret_cast<const short8*>(qkv + (size_t)(b*NT + tok)*QKVN + 2*DM + h*HD + dc);
#pragma unroll
    for (int j = 0; j < 8; ++j) o[j] += s[kj] * bf2f(vv[j]);
  }
  short8 ov;
#pragma unroll
  for (int j = 0; j < 8; ++j) ov[j] = f2bf(o[j] * inv);
  *reinterpret_cast<short8*>(aout + (size_t)(b*NT + tokq)*DM + h*HD + dc) = ov;
}

// ---------------- space attention (MFMA): group=(b,h,frame), 196 q x 197 k ----------------
#define PST 232
#define VST 232
__global__ __launch_bounds__(256) void space_attn_mfma(const s16* __restrict__ qkv,
                                                       s16* __restrict__ aout) {
  __shared__ s16 Vt[64][VST];
  __shared__ s16 P[4][16][PST];
  int grp = blockIdx.x;
  int fr = grp & 7; int bh = grp >> 3; int b = bh / NH, h = bh % NH;
  int tid = threadIdx.x, w = tid >> 6, lane = tid & 63;
  const size_t hbase = (size_t)(b * NT) * QKVN + h * HD;

  for (int idx = tid; idx < 224 * 8; idx += 256) {
    int kj = idx >> 3, c8 = idx & 7;
    if (kj < 197) {
      int tok = (kj == 0) ? 0 : (1 + fr * NP + kj - 1);
      short8 vv = *reinterpret_cast<const short8*>(qkv + hbase + (size_t)tok * QKVN + 2 * DM + c8 * 8);
#pragma unroll
      for (int j = 0; j < 8; ++j) Vt[c8 * 8 + j][kj] = vv[j];
    } else {
#pragma unroll
      for (int j = 0; j < 8; ++j) Vt[c8 * 8 + j][kj] = 0;
    }
  }
  for (int i = tid; i < 4 * 16 * 16; i += 256) {
    int wv = i >> 8, rr = (i >> 4) & 15, cc = i & 15;
    P[wv][rr][208 + cc] = 0;
  }
  __syncthreads();

  const int lr = lane & 15, lg = lane >> 4;

  for (int t0 = w; t0 < 13; t0 += 4) {
    int q0 = t0 * 16;
    short8 aq[2];
#pragma unroll
    for (int c = 0; c < 2; ++c) {
      int tokq = 1 + fr * NP + q0 + lr;
      aq[c] = *reinterpret_cast<const short8*>(qkv + hbase + (size_t)tokq * QKVN + c * 32 + lg * 8);
    }
    short8 kb[13][2];
#pragma unroll
    for (int t = 0; t < 13; ++t) {
#pragma unroll
      for (int c = 0; c < 2; ++c) {
        int krow = t * 16 + lr;
        int tokk = (krow == 0) ? 0 : (1 + fr * NP + krow - 1);
        kb[t][c] = *reinterpret_cast<const short8*>(qkv + hbase + (size_t)tokk * QKVN + DM + c * 32 + lg * 8);
      }
    }
    floatx4 st[13];
#pragma unroll
    for (int t = 0; t < 13; ++t) st[t] = (floatx4){0.f, 0.f, 0.f, 0.f};
#pragma unroll
    for (int t = 0; t < 13; ++t) {
      st[t] = __builtin_amdgcn_mfma_f32_16x16x32_bf16(aq[0], kb[t][0], st[t], 0, 0, 0);
      st[t] = __builtin_amdgcn_mfma_f32_16x16x32_bf16(aq[1], kb[t][1], st[t], 0, 0, 0);
    }
    float mj[4] = {-1e30f, -1e30f, -1e30f, -1e30f};
#pragma unroll
    for (int t = 0; t < 13; ++t) {
      int key = t * 16 + lr;
#pragma unroll
      for (int j = 0; j < 4; ++j) {
        float v = (key < 197) ? st[t][j] * 0.125f : -1e30f;
        st[t][j] = v;
        mj[j] = fmaxf(mj[j], v);
      }
    }
#pragma unroll
    for (int j = 0; j < 4; ++j) {
      mj[j] = fmaxf(mj[j], __shfl_xor(mj[j], 1));
      mj[j] = fmaxf(mj[j], __shfl_xor(mj[j], 2));
      mj[j] = fmaxf(mj[j], __shfl_xor(mj[j], 4));
      mj[j] = fmaxf(mj[j], __shfl_xor(mj[j], 8));
    }
    float su[4] = {0.f, 0.f, 0.f, 0.f};
#pragma unroll
    for (int t = 0; t < 13; ++t)
#pragma unroll
      for (int j = 0; j < 4; ++j) {
        float e = __expf(st[t][j] - mj[j]);
        st[t][j] = e;
        su[j] += e;
      }
#pragma unroll
    for (int j = 0; j < 4; ++j) {
      su[j] += __shfl_xor(su[j], 1);
      su[j] += __shfl_xor(su[j], 2);
      su[j] += __shfl_xor(su[j], 4);
      su[j] += __shfl_xor(su[j], 8);
    }
    float inv[4];
#pragma unroll
    for (int j = 0; j < 4; ++j) inv[j] = 1.0f / su[j];
#pragma unroll
    for (int t = 0; t < 13; ++t)
#pragma unroll
      for (int j = 0; j < 4; ++j)
        P[w][lg * 4 + j][t * 16 + lr] = f2bf(st[t][j]);
    floatx4 o[4];
#pragma unroll
    for (int dt = 0; dt < 4; ++dt) o[dt] = (floatx4){0.f, 0.f, 0.f, 0.f};
#pragma unroll
    for (int kc = 0; kc < 7; ++kc) {
      short8 pa = *reinterpret_cast<const short8*>(&P[w][lr][kc * 32 + lg * 8]);
#pragma unroll
      for (int dt = 0; dt < 4; ++dt) {
        short8 vb = *reinterpret_cast<const short8*>(&Vt[dt * 16 + lr][kc * 32 + lg * 8]);
        o[dt] = __builtin_amdgcn_mfma_f32_16x16x32_bf16(pa, vb, o[dt], 0, 0, 0);
      }
    }
#pragma unroll
    for (int dt = 0; dt < 4; ++dt)
#pragma unroll
      for (int j = 0; j < 4; ++j) {
        int q = q0 + lg * 4 + j;
        if (q < NP) {
          int tokq = 1 + fr * NP + q;
          aout[(size_t)(b * NT + tokq) * DM + h * HD + dt * 16 + lr] = f2bf(o[dt][j] * inv[j]);
        }
      }
  }
}

// ---------------- host launcher ----------------
extern "C" void kernel_launch(void* const* d_in, const int* in_sizes, int n_in,
                              void* d_out, int out_size, void* d_ws, size_t ws_size,
                              hipStream_t stream) {
  const float* x       = (const float*)d_in[0];
  const float* n1g     = (const float*)d_in[1];
  const float* n1b     = (const float*)d_in[2];
  const float* n2g     = (const float*)d_in[3];
  const float* n2b     = (const float*)d_in[4];
  const float* n3g     = (const float*)d_in[5];
  const float* n3b     = (const float*)d_in[6];
  const float* aqkv_w  = (const float*)d_in[7];
  const float* aqkv_b  = (const float*)d_in[8];
  const float* aproj_w = (const float*)d_in[9];
  const float* aproj_b = (const float*)d_in[10];
  const float* tqkv_w  = (const float*)d_in[11];
  const float* tqkv_b  = (const float*)d_in[12];
  const float* tproj_w = (const float*)d_in[13];
  const float* tproj_b = (const float*)d_in[14];
  const float* fc1_w   = (const float*)d_in[15];
  const float* fc1_b   = (const float*)d_in[16];
  const float* fc2_w   = (const float*)d_in[17];
  const float* fc2_b   = (const float*)d_in[18];
  float* out = (float*)d_out;

  char* ws = (char*)d_ws;
  size_t off = 0;
  auto alloc = [&](size_t bytes) -> void* {
    void* p = ws + off;
    off += (bytes + 255) & ~(size_t)255;
    return p;
  };
  s16*  wt_tqkv  = (s16*)alloc((size_t)QKVN * DM * 2);
  s16*  wt_tproj = (s16*)alloc((size_t)DM * DM * 2);
  s16*  wt_aqkv  = (s16*)alloc((size_t)QKVN * DM * 2);
  s16*  wt_aproj = (s16*)alloc((size_t)DM * DM * 2);
  s16*  wt_fc1   = (s16*)alloc((size_t)FCN * DM * 2);
  s16*  wt_fc2   = (s16*)alloc((size_t)DM * FCN * 2);
  s16*  ln_out   = (s16*)alloc((size_t)MPAD * DM * 2);
  s16*  attnout  = (s16*)alloc((size_t)MPAD * DM * 2);
  float* resid_s = (float*)alloc((size_t)MROWS * DM * 4);
  char* big      = (char*)alloc((size_t)MPAD * FCN * 2);  // union: qkv_buf / resid_t / h_buf
  s16*   qkv_buf = (s16*)big;
  float* resid_t = (float*)big;
  s16*   h_buf   = (s16*)big;

  dim3 tb(32, 8);
  wtrans<<<dim3(QKVN/32, DM/32), tb, 0, stream>>>(tqkv_w,  wt_tqkv,  DM, QKVN);
  wtrans<<<dim3(DM/32,   DM/32), tb, 0, stream>>>(tproj_w, wt_tproj, DM, DM);
  wtrans<<<dim3(QKVN/32, DM/32), tb, 0, stream>>>(aqkv_w,  wt_aqkv,  DM, QKVN);
  wtrans<<<dim3(DM/32,   DM/32), tb, 0, stream>>>(aproj_w, wt_aproj, DM, DM);
  wtrans<<<dim3(FCN/32,  DM/32), tb, 0, stream>>>(fc1_w,   wt_fc1,   DM, FCN);
  wtrans<<<dim3(DM/32,  FCN/32), tb, 0, stream>>>(fc2_w,   wt_fc2,   FCN, DM);

  const int XT_QKV = QKVN / 256, XT_PRJ = DM / 256, XT_FC1 = FCN / 256;

  // ---- time branch ----
  ln_k<<<MROWS, 256, 0, stream>>>(x, n3g, n3b, ln_out);
  gemm256<0><<<XT_QKV * MT, 512, 0, stream>>>(ln_out, wt_tqkv, tqkv_b, nullptr, qkv_buf, DM, QKVN, XT_QKV);
  cls_attn<<<BB*NH, 256, 0, stream>>>(qkv_buf, attnout);
  time_attn<<<(BB*NH*NP)/4, 256, 0, stream>>>(qkv_buf, attnout);
  gemm256<2><<<XT_PRJ * MT, 512, 0, stream>>>(attnout, wt_tproj, tproj_b, x, resid_t, DM, DM, XT_PRJ);

  // ---- space branch ----
  ln_k<<<MROWS, 256, 0, stream>>>(resid_t, n1g, n1b, ln_out);
  gemm256<0><<<XT_QKV * MT, 512, 0, stream>>>(ln_out, wt_aqkv, aqkv_b, nullptr, qkv_buf, DM, QKVN, XT_QKV);
  cls_attn<<<BB*NH, 256, 0, stream>>>(qkv_buf, attnout);
  space_attn_mfma<<<BB*NH*FF, 256, 0, stream>>>(qkv_buf, attnout);
  gemm256<2><<<XT_PRJ * MT, 512, 0, stream>>>(attnout, wt_aproj, aproj_b, x, resid_s, DM, DM, XT_PRJ);

  // ---- MLP ----
  ln_k<<<MROWS, 256, 0, stream>>>(resid_s, n2g, n2b, ln_out);
  gemm256<1><<<XT_FC1 * MT, 512, 0, stream>>>(ln_out, wt_fc1, fc1_b, nullptr, h_buf, DM, FCN, XT_FC1);
  gemm256<2><<<XT_PRJ * MT, 512, 0, stream>>>(h_buf, wt_fc2, fc2_b, resid_s, out, FCN, DM, XT_PRJ);
}

// Round 4
// 974.445 us; speedup vs baseline: 1.0623x; 1.0623x over previous
//
#include <hip/hip_runtime.h>
#include <hip/hip_bf16.h>
#include <math.h>

// ---------------- problem constants (from setup_inputs) ----------------
#define DM    768           // model dim
#define NH    12            // heads
#define HD    64            // head dim
#define BB    8             // batch
#define FF    8             // frames
#define NP    196           // spatial positions
#define NT    1569          // 1 + FF*NP tokens
#define MROWS 12552         // BB*NT
#define MPAD  12672         // buffer row padding (allocation only; 99*128)
#define MT    50            // ceil(MROWS/256) row tiles for 256^2 GEMM
#define QKVN  2304          // 3*DM
#define FCN   3072          // 4*DM

typedef short s16;          // bf16 stored as raw 16-bit
typedef __attribute__((ext_vector_type(8))) short short8;
typedef __attribute__((ext_vector_type(4))) float floatx4;

__device__ __forceinline__ float bf2f(s16 s) {
  union { unsigned u; float f; } x;
  x.u = ((unsigned)(unsigned short)s) << 16;
  return x.f;
}
__device__ __forceinline__ s16 f2bf(float f) {
  __hip_bfloat16 h = __float2bfloat16(f);
  s16 r;
  __builtin_memcpy(&r, &h, sizeof(r));
  return r;
}
__device__ __forceinline__ void gload16(const void* g, void* l) {
  __builtin_amdgcn_global_load_lds(
      (__attribute__((address_space(1))) void*)g,
      (__attribute__((address_space(3))) void*)l, 16, 0, 0);
}

// ---------------- weight transpose + fp32->bf16 convert ----------------
__global__ void wtrans(const float* __restrict__ W, s16* __restrict__ Wt,
                       int K, int Nn) {
  __shared__ float t[32][33];
  int n0 = blockIdx.x * 32, k0 = blockIdx.y * 32;
  int tx = threadIdx.x, ty = threadIdx.y;   // (32,8)
#pragma unroll
  for (int i = 0; i < 4; ++i)
    t[ty + 8*i][tx] = W[(size_t)(k0 + ty + 8*i) * Nn + n0 + tx];
  __syncthreads();
#pragma unroll
  for (int i = 0; i < 4; ++i)
    Wt[(size_t)(n0 + ty + 8*i) * K + k0 + tx] = f2bf(t[tx][ty + 8*i]);
}

// ---------------- LayerNorm fp32 -> bf16 ----------------
__global__ __launch_bounds__(256) void ln_k(const float* __restrict__ in,
                                            const float* __restrict__ g,
                                            const float* __restrict__ b,
                                            s16* __restrict__ out) {
  __shared__ float red[8];
  int row = blockIdx.x;
  int tid = threadIdx.x;
  const float* rp = in + (size_t)row * DM;
  float v0 = rp[tid], v1 = rp[tid + 256], v2 = rp[tid + 512];
  float s = v0 + v1 + v2;
#pragma unroll
  for (int o = 32; o; o >>= 1) s += __shfl_down(s, o);
  if ((tid & 63) == 0) red[tid >> 6] = s;
  __syncthreads();
  float mean = (red[0] + red[1] + red[2] + red[3]) * (1.0f / DM);
  __syncthreads();
  float d0 = v0 - mean, d1 = v1 - mean, d2 = v2 - mean;
  float q = d0*d0 + d1*d1 + d2*d2;
#pragma unroll
  for (int o = 32; o; o >>= 1) q += __shfl_down(q, o);
  if ((tid & 63) == 0) red[tid >> 6] = q;
  __syncthreads();
  float var = (red[0] + red[1] + red[2] + red[3]) * (1.0f / DM);
  float rs = rsqrtf(var + 1e-5f);
  s16* op = out + (size_t)row * DM;
  op[tid      ] = f2bf(d0 * rs * g[tid      ] + b[tid      ]);
  op[tid + 256] = f2bf(d1 * rs * g[tid + 256] + b[tid + 256]);
  op[tid + 512] = f2bf(d2 * rs * g[tid + 512] + b[tid + 512]);
}

// ---------------- 256x256 8-phase deep-pipelined bf16 MFMA GEMM ----------------
// Corrected T2 swizzle (3-bit): LDS[row][c] holds global[row][c ^ ((row&7)<<3)]
// (elems; byte form (row&7)<<4). gload_lds dest stays linear; the XOR is applied
// to the GLOBAL source col on stage and to the col on ds_read (same involution).
// EPI: 0 = bias->bf16 ; 1 = bias+GELU->bf16 ; 2 = bias+resid->fp32
template<int EPI>
__global__ __launch_bounds__(512, 2) void gemm256(const s16* __restrict__ A,
                                                  const s16* __restrict__ Bt,
                                                  const float* __restrict__ bias,
                                                  const float* __restrict__ resid,
                                                  void* __restrict__ out,
                                                  int K, int Nn, int xt) {
  __shared__ s16 As[2][256 * 64];
  __shared__ s16 Bs[2][256 * 64];
  // bijective XCD swizzle (m204)
  const int nwg = gridDim.x, orig = blockIdx.x;
  const int qq = nwg >> 3, rr = nwg & 7, xcd = orig & 7, lid = orig >> 3;
  const int wgid = (xcd < rr ? xcd * (qq + 1) : rr * (qq + 1) + (xcd - rr) * qq) + lid;
  const int bx = wgid % xt, by = wgid / xt;
  const int row0 = by * 256, col0 = bx * 256;
  const int tid = threadIdx.x, lane = tid & 63, w = tid >> 6;
  const int wr = w >> 2, wc = w & 3;
  const int lr = lane & 15, hi = lane >> 4;
  const int nt = K >> 6;

  const int srow = tid >> 3;                                   // 0..63
  const int colg = ((lane & 7) * 8) ^ ((srow & 7) << 3);       // inverse-swizzled src col
  const int ldsc = (lane & 7) * 8;                             // linear LDS col (elems)

#define STAGE_A(half, k0s)                                                        \
  {                                                                               \
    _Pragma("unroll")                                                             \
    for (int i = 0; i < 2; ++i) {                                                 \
      int rl = (half) * 128 + i * 64 + srow;                                      \
      int rg = row0 + rl; if (rg > MROWS - 1) rg = MROWS - 1;                     \
      gload16(A + (size_t)rg * K + (k0s) + colg, Adst + rl * 64 + ldsc);          \
    }                                                                             \
  }
#define STAGE_B(half, k0s, Bd)                                                    \
  {                                                                               \
    _Pragma("unroll")                                                             \
    for (int i = 0; i < 2; ++i) {                                                 \
      int rl = (half) * 128 + i * 64 + srow;                                      \
      gload16(Bt + (size_t)(col0 + rl) * K + (k0s) + colg, (Bd) + rl * 64 + ldsc);\
    }                                                                             \
  }

  // ---- prologue ----
  {
    s16* Adst = As[0];
    STAGE_A(0, 0) STAGE_A(1, 0)
    STAGE_B(0, 0, Bs[0]) STAGE_B(1, 0, Bs[0])
    int k1 = 64;
    STAGE_B(0, k1, Bs[1]) STAGE_B(1, k1, Bs[1])
  }
  asm volatile("s_waitcnt vmcnt(4)" ::: "memory");
  __builtin_amdgcn_s_barrier();

  floatx4 acc[8][4] = {};
  const int rdswz = (lr & 7) << 3;           // full 3-bit read-side swizzle (elems)

  for (int kt = 0; kt < nt; ++kt) {
    const int bb = kt & 1;
    const s16* Ab = As[bb];
    const s16* Bb = Bs[bb];
    s16* Adst = As[bb ^ 1];
    s16* Bdst = Bs[bb];                      // free after ph0 (bq fully consumed)
    const int ka  = ((kt + 1) < nt ? (kt + 1) : 0) * 64;
    const int kb2 = ((kt + 2) < nt ? (kt + 2) : (kt + 2 - nt)) * 64;

    short8 bq[4][2];
#pragma unroll
    for (int ni = 0; ni < 4; ++ni)
#pragma unroll
      for (int ks = 0; ks < 2; ++ks)
        bq[ni][ks] = *reinterpret_cast<const short8*>(
            Bb + (wc * 64 + ni * 16 + lr) * 64 + ((ks * 32 + hi * 8) ^ rdswz));

#pragma unroll
    for (int ph = 0; ph < 4; ++ph) {
      short8 aq[2][2];
#pragma unroll
      for (int m = 0; m < 2; ++m)
#pragma unroll
        for (int ks = 0; ks < 2; ++ks)
          aq[m][ks] = *reinterpret_cast<const short8*>(
              Ab + (wr * 128 + (ph * 2 + m) * 16 + lr) * 64 + ((ks * 32 + hi * 8) ^ rdswz));
      if (ph == 0)      STAGE_A(0, ka)
      else if (ph == 1) STAGE_A(1, ka)
      else if (ph == 2) STAGE_B(0, kb2, Bdst)
      else              STAGE_B(1, kb2, Bdst)
      __builtin_amdgcn_s_barrier();
      __builtin_amdgcn_s_setprio(1);
#pragma unroll
      for (int ni = 0; ni < 4; ++ni)
#pragma unroll
        for (int m = 0; m < 2; ++m) {
          acc[ph * 2 + m][ni] = __builtin_amdgcn_mfma_f32_16x16x32_bf16(
              aq[m][0], bq[ni][0], acc[ph * 2 + m][ni], 0, 0, 0);
          acc[ph * 2 + m][ni] = __builtin_amdgcn_mfma_f32_16x16x32_bf16(
              aq[m][1], bq[ni][1], acc[ph * 2 + m][ni], 0, 0, 0);
        }
      __builtin_amdgcn_s_setprio(0);
      if (ph == 3) asm volatile("s_waitcnt vmcnt(4)" ::: "memory");
      __builtin_amdgcn_s_barrier();
    }
  }
#undef STAGE_A
#undef STAGE_B

#pragma unroll
  for (int mi = 0; mi < 8; ++mi) {
#pragma unroll
    for (int j = 0; j < 4; ++j) {
      int r = row0 + wr * 128 + mi * 16 + hi * 4 + j;
      if (r >= MROWS) continue;
#pragma unroll
      for (int ni = 0; ni < 4; ++ni) {
        int c = col0 + wc * 64 + ni * 16 + lr;
        float v = acc[mi][ni][j] + bias[c];
        size_t idx = (size_t)r * Nn + c;
        if (EPI == 0) {
          ((s16*)out)[idx] = f2bf(v);
        } else if (EPI == 1) {
          float ge = 0.5f * v * (1.0f + erff(v * 0.70710678118654752f));
          ((s16*)out)[idx] = f2bf(ge);
        } else {
          ((float*)out)[idx] = resid[idx] + v;
        }
      }
    }
  }
}

// ---------------- 128x128 2-phase BK=64 bf16 MFMA GEMM ----------------
// Proven R2 structure, but TWO [128][32] buffer pairs per operand: BK=64
// halves the syncthreads drains per K while keeping the conflict-free
// [128][32] read pattern (no swizzle needed). 4 waves, 2x2 wave grid.
template<int EPI>
__global__ __launch_bounds__(256) void gemm128(const s16* __restrict__ A,
                                               const s16* __restrict__ Bt,
                                               const float* __restrict__ bias,
                                               const float* __restrict__ resid,
                                               void* __restrict__ out,
                                               int K, int Nn) {
  __shared__ s16 As0[128 * 32], As1[128 * 32];
  __shared__ s16 Bs0[128 * 32], Bs1[128 * 32];
  const int tid = threadIdx.x;
  const int wave = tid >> 6, lane = tid & 63;
  const int row0 = blockIdx.y * 128, col0 = blockIdx.x * 128;
  const int wr = wave >> 1, wc = wave & 1;
  const int lrow = lane & 15, lk = (lane >> 4) * 8;

  floatx4 acc[4][4] = {};

  for (int k0 = 0; k0 < K; k0 += 64) {
#pragma unroll
    for (int i = 0; i < 2; ++i) {
      int elem = ((i * 4 + wave) << 9) + (lane << 3);   // [128][32] linear
      int r = elem >> 5, c = elem & 31;
      const s16* Ap = A  + (size_t)(row0 + r) * K + k0 + c;
      const s16* Bp = Bt + (size_t)(col0 + r) * K + k0 + c;
      gload16(Ap,      As0 + elem);
      gload16(Ap + 32, As1 + elem);
      gload16(Bp,      Bs0 + elem);
      gload16(Bp + 32, Bs1 + elem);
    }
    __syncthreads();
    short8 af0[4], af1[4], bf0[4], bf1[4];
#pragma unroll
    for (int mi = 0; mi < 4; ++mi) {
      int ro = ((wr * 64 + mi * 16 + lrow) << 5) + lk;
      af0[mi] = *reinterpret_cast<const short8*>(As0 + ro);
      af1[mi] = *reinterpret_cast<const short8*>(As1 + ro);
    }
#pragma unroll
    for (int ni = 0; ni < 4; ++ni) {
      int ro = ((wc * 64 + ni * 16 + lrow) << 5) + lk;
      bf0[ni] = *reinterpret_cast<const short8*>(Bs0 + ro);
      bf1[ni] = *reinterpret_cast<const short8*>(Bs1 + ro);
    }
#pragma unroll
    for (int mi = 0; mi < 4; ++mi)
#pragma unroll
      for (int ni = 0; ni < 4; ++ni) {
        acc[mi][ni] = __builtin_amdgcn_mfma_f32_16x16x32_bf16(af0[mi], bf0[ni], acc[mi][ni], 0, 0, 0);
        acc[mi][ni] = __builtin_amdgcn_mfma_f32_16x16x32_bf16(af1[mi], bf1[ni], acc[mi][ni], 0, 0, 0);
      }
    __syncthreads();
  }

  const int c_lane = lane & 15, r_lane = lane >> 4;
#pragma unroll
  for (int mi = 0; mi < 4; ++mi) {
#pragma unroll
    for (int j = 0; j < 4; ++j) {
      int r = row0 + wr * 64 + mi * 16 + r_lane * 4 + j;
      if (r >= MROWS) continue;
#pragma unroll
      for (int ni = 0; ni < 4; ++ni) {
        int c = col0 + wc * 64 + ni * 16 + c_lane;
        float v = acc[mi][ni][j] + bias[c];
        size_t idx = (size_t)r * Nn + c;
        if (EPI == 0) {
          ((s16*)out)[idx] = f2bf(v);
        } else if (EPI == 1) {
          float ge = 0.5f * v * (1.0f + erff(v * 0.70710678118654752f));
          ((s16*)out)[idx] = f2bf(ge);
        } else {
          ((float*)out)[idx] = resid[idx] + v;
        }
      }
    }
  }
}

// ---------------- cls-token attention: 1 query over all NT keys ----------------
__global__ __launch_bounds__(256) void cls_attn(const s16* __restrict__ qkv,
                                                s16* __restrict__ aout) {
  __shared__ float qs[64];
  __shared__ float sc[NT];
  __shared__ float pacc[4][64];
  __shared__ float red[8];
  int bh = blockIdx.x; int b = bh / NH, h = bh % NH;
  int tid = threadIdx.x;
  if (tid < 64) qs[tid] = 0.125f * bf2f(qkv[(size_t)(b*NT) * QKVN + h*HD + tid]);
  __syncthreads();
  for (int t = tid; t < NT; t += 256) {
    const s16* kp = qkv + (size_t)(b*NT + t) * QKVN + DM + h*HD;
    float dot = 0.f;
#pragma unroll
    for (int d8 = 0; d8 < 8; ++d8) {
      short8 kv = *reinterpret_cast<const short8*>(kp + d8*8);
#pragma unroll
      for (int j = 0; j < 8; ++j) dot += qs[d8*8 + j] * bf2f(kv[j]);
    }
    sc[t] = dot;
  }
  __syncthreads();
  float m = -1e30f;
  for (int t = tid; t < NT; t += 256) m = fmaxf(m, sc[t]);
#pragma unroll
  for (int o = 32; o; o >>= 1) m = fmaxf(m, __shfl_xor(m, o));
  if ((tid & 63) == 0) red[tid >> 6] = m;
  __syncthreads();
  m = fmaxf(fmaxf(red[0], red[1]), fmaxf(red[2], red[3]));
  __syncthreads();
  float s = 0.f;
  for (int t = tid; t < NT; t += 256) { float e = expf(sc[t] - m); sc[t] = e; s += e; }
#pragma unroll
  for (int o = 32; o; o >>= 1) s += __shfl_xor(s, o);
  if ((tid & 63) == 0) red[tid >> 6] = s;
  __syncthreads();
  float inv = 1.0f / (red[0] + red[1] + red[2] + red[3]);
  int d = tid & 63, part = tid >> 6;
  float a = 0.f;
  for (int t = part; t < NT; t += 4)
    a += sc[t] * bf2f(qkv[(size_t)(b*NT + t) * QKVN + 2*DM + h*HD + d]);
  pacc[part][d] = a;
  __syncthreads();
  if (tid < 64) {
    float o = (pacc[0][tid] + pacc[1][tid] + pacc[2][tid] + pacc[3][tid]) * inv;
    aout[(size_t)(b*NT) * DM + h*HD + tid] = f2bf(o);
  }
}

// ---------------- time attention: group=(b,h,p), 8 queries x 9 keys ----------------
__global__ __launch_bounds__(256) void time_attn(const s16* __restrict__ qkv,
                                                 s16* __restrict__ aout) {
  int g = blockIdx.x * 4 + (threadIdx.x >> 6);
  int lane = threadIdx.x & 63;
  int p = g % NP; int bh = g / NP; int b = bh / NH, h = bh % NH;
  int qi = lane >> 3;
  int dc = (lane & 7) * 8;
  int tokq = 1 + qi*NP + p;
  short8 qv = *reinterpret_cast<const short8*>(qkv + (size_t)(b*NT + tokq)*QKVN + h*HD + dc);
  float qf[8];
#pragma unroll
  for (int j = 0; j < 8; ++j) qf[j] = 0.125f * bf2f(qv[j]);
  float s[9];
#pragma unroll
  for (int kj = 0; kj < 9; ++kj) {
    int tok = (kj == 0) ? 0 : (1 + (kj - 1)*NP + p);
    short8 kv = *reinterpret_cast<const short8*>(qkv + (size_t)(b*NT + tok)*QKVN + DM + h*HD + dc);
    float d = 0.f;
#pragma unroll
    for (int j = 0; j < 8; ++j) d += qf[j] * bf2f(kv[j]);
    d += __shfl_xor(d, 1); d += __shfl_xor(d, 2); d += __shfl_xor(d, 4);
    s[kj] = d;
  }
  float m = s[0];
#pragma unroll
  for (int kj = 1; kj < 9; ++kj) m = fmaxf(m, s[kj]);
  float sum = 0.f;
#pragma unroll
  for (int kj = 0; kj < 9; ++kj) { s[kj] = expf(s[kj] - m); sum += s[kj]; }
  float inv = 1.0f / sum;
  float o[8] = {0,0,0,0,0,0,0,0};
#pragma unroll
  for (int kj = 0; kj < 9; ++kj) {
    int tok = (kj == 0) ? 0 : (1 + (kj - 1)*NP + p);
    short8 vv = *reinterpret_cast<const short8*>(qkv + (size_t)(b*NT + tok)*QKVN + 2*DM + h*HD + dc);
#pragma unroll
    for (int j = 0; j < 8; ++j) o[j] += s[kj] * bf2f(vv[j]);
  }
  short8 ov;
#pragma unroll
  for (int j = 0; j < 8; ++j) ov[j] = f2bf(o[j] * inv);
  *reinterpret_cast<short8*>(aout + (size_t)(b*NT + tokq)*DM + h*HD + dc) = ov;
}

// ---------------- space attention (MFMA): group=(b,h,frame), 196 q x 197 k ----------------
#define PST 232
#define VST 232
__global__ __launch_bounds__(256) void space_attn_mfma(const s16* __restrict__ qkv,
                                                       s16* __restrict__ aout) {
  __shared__ s16 Vt[64][VST];
  __shared__ s16 P[4][16][PST];
  int grp = blockIdx.x;
  int fr = grp & 7; int bh = grp >> 3; int b = bh / NH, h = bh % NH;
  int tid = threadIdx.x, w = tid >> 6, lane = tid & 63;
  const size_t hbase = (size_t)(b * NT) * QKVN + h * HD;

  for (int idx = tid; idx < 224 * 8; idx += 256) {
    int kj = idx >> 3, c8 = idx & 7;
    if (kj < 197) {
      int tok = (kj == 0) ? 0 : (1 + fr * NP + kj - 1);
      short8 vv = *reinterpret_cast<const short8*>(qkv + hbase + (size_t)tok * QKVN + 2 * DM + c8 * 8);
#pragma unroll
      for (int j = 0; j < 8; ++j) Vt[c8 * 8 + j][kj] = vv[j];
    } else {
#pragma unroll
      for (int j = 0; j < 8; ++j) Vt[c8 * 8 + j][kj] = 0;
    }
  }
  for (int i = tid; i < 4 * 16 * 16; i += 256) {
    int wv = i >> 8, rr2 = (i >> 4) & 15, cc = i & 15;
    P[wv][rr2][208 + cc] = 0;
  }
  __syncthreads();

  const int lr = lane & 15, lg = lane >> 4;

  for (int t0 = w; t0 < 13; t0 += 4) {
    int q0 = t0 * 16;
    short8 aq[2];
#pragma unroll
    for (int c = 0; c < 2; ++c) {
      int tokq = 1 + fr * NP + q0 + lr;
      aq[c] = *reinterpret_cast<const short8*>(qkv + hbase + (size_t)tokq * QKVN + c * 32 + lg * 8);
    }
    short8 kb[13][2];
#pragma unroll
    for (int t = 0; t < 13; ++t) {
#pragma unroll
      for (int c = 0; c < 2; ++c) {
        int krow = t * 16 + lr;
        int tokk = (krow == 0) ? 0 : (1 + fr * NP + krow - 1);
        kb[t][c] = *reinterpret_cast<const short8*>(qkv + hbase + (size_t)tokk * QKVN + DM + c * 32 + lg * 8);
      }
    }
    floatx4 st[13];
#pragma unroll
    for (int t = 0; t < 13; ++t) st[t] = (floatx4){0.f, 0.f, 0.f, 0.f};
#pragma unroll
    for (int t = 0; t < 13; ++t) {
      st[t] = __builtin_amdgcn_mfma_f32_16x16x32_bf16(aq[0], kb[t][0], st[t], 0, 0, 0);
      st[t] = __builtin_amdgcn_mfma_f32_16x16x32_bf16(aq[1], kb[t][1], st[t], 0, 0, 0);
    }
    float mj[4] = {-1e30f, -1e30f, -1e30f, -1e30f};
#pragma unroll
    for (int t = 0; t < 13; ++t) {
      int key = t * 16 + lr;
#pragma unroll
      for (int j = 0; j < 4; ++j) {
        float v = (key < 197) ? st[t][j] * 0.125f : -1e30f;
        st[t][j] = v;
        mj[j] = fmaxf(mj[j], v);
      }
    }
#pragma unroll
    for (int j = 0; j < 4; ++j) {
      mj[j] = fmaxf(mj[j], __shfl_xor(mj[j], 1));
      mj[j] = fmaxf(mj[j], __shfl_xor(mj[j], 2));
      mj[j] = fmaxf(mj[j], __shfl_xor(mj[j], 4));
      mj[j] = fmaxf(mj[j], __shfl_xor(mj[j], 8));
    }
    float su[4] = {0.f, 0.f, 0.f, 0.f};
#pragma unroll
    for (int t = 0; t < 13; ++t)
#pragma unroll
      for (int j = 0; j < 4; ++j) {
        float e = __expf(st[t][j] - mj[j]);
        st[t][j] = e;
        su[j] += e;
      }
#pragma unroll
    for (int j = 0; j < 4; ++j) {
      su[j] += __shfl_xor(su[j], 1);
      su[j] += __shfl_xor(su[j], 2);
      su[j] += __shfl_xor(su[j], 4);
      su[j] += __shfl_xor(su[j], 8);
    }
    float inv[4];
#pragma unroll
    for (int j = 0; j < 4; ++j) inv[j] = 1.0f / su[j];
#pragma unroll
    for (int t = 0; t < 13; ++t)
#pragma unroll
      for (int j = 0; j < 4; ++j)
        P[w][lg * 4 + j][t * 16 + lr] = f2bf(st[t][j]);
    floatx4 o[4];
#pragma unroll
    for (int dt = 0; dt < 4; ++dt) o[dt] = (floatx4){0.f, 0.f, 0.f, 0.f};
#pragma unroll
    for (int kc = 0; kc < 7; ++kc) {
      short8 pa = *reinterpret_cast<const short8*>(&P[w][lr][kc * 32 + lg * 8]);
#pragma unroll
      for (int dt = 0; dt < 4; ++dt) {
        short8 vb = *reinterpret_cast<const short8*>(&Vt[dt * 16 + lr][kc * 32 + lg * 8]);
        o[dt] = __builtin_amdgcn_mfma_f32_16x16x32_bf16(pa, vb, o[dt], 0, 0, 0);
      }
    }
#pragma unroll
    for (int dt = 0; dt < 4; ++dt)
#pragma unroll
      for (int j = 0; j < 4; ++j) {
        int q = q0 + lg * 4 + j;
        if (q < NP) {
          int tokq = 1 + fr * NP + q;
          aout[(size_t)(b * NT + tokq) * DM + h * HD + dt * 16 + lr] = f2bf(o[dt][j] * inv[j]);
        }
      }
  }
}

// ---------------- host launcher ----------------
extern "C" void kernel_launch(void* const* d_in, const int* in_sizes, int n_in,
                              void* d_out, int out_size, void* d_ws, size_t ws_size,
                              hipStream_t stream) {
  const float* x       = (const float*)d_in[0];
  const float* n1g     = (const float*)d_in[1];
  const float* n1b     = (const float*)d_in[2];
  const float* n2g     = (const float*)d_in[3];
  const float* n2b     = (const float*)d_in[4];
  const float* n3g     = (const float*)d_in[5];
  const float* n3b     = (const float*)d_in[6];
  const float* aqkv_w  = (const float*)d_in[7];
  const float* aqkv_b  = (const float*)d_in[8];
  const float* aproj_w = (const float*)d_in[9];
  const float* aproj_b = (const float*)d_in[10];
  const float* tqkv_w  = (const float*)d_in[11];
  const float* tqkv_b  = (const float*)d_in[12];
  const float* tproj_w = (const float*)d_in[13];
  const float* tproj_b = (const float*)d_in[14];
  const float* fc1_w   = (const float*)d_in[15];
  const float* fc1_b   = (const float*)d_in[16];
  const float* fc2_w   = (const float*)d_in[17];
  const float* fc2_b   = (const float*)d_in[18];
  float* out = (float*)d_out;

  char* ws = (char*)d_ws;
  size_t off = 0;
  auto alloc = [&](size_t bytes) -> void* {
    void* p = ws + off;
    off += (bytes + 255) & ~(size_t)255;
    return p;
  };
  s16*  wt_tqkv  = (s16*)alloc((size_t)QKVN * DM * 2);
  s16*  wt_tproj = (s16*)alloc((size_t)DM * DM * 2);
  s16*  wt_aqkv  = (s16*)alloc((size_t)QKVN * DM * 2);
  s16*  wt_aproj = (s16*)alloc((size_t)DM * DM * 2);
  s16*  wt_fc1   = (s16*)alloc((size_t)FCN * DM * 2);
  s16*  wt_fc2   = (s16*)alloc((size_t)DM * FCN * 2);
  s16*  ln_out   = (s16*)alloc((size_t)MPAD * DM * 2);
  s16*  attnout  = (s16*)alloc((size_t)MPAD * DM * 2);
  float* resid_s = (float*)alloc((size_t)MROWS * DM * 4);
  char* big      = (char*)alloc((size_t)MPAD * FCN * 2);  // union: qkv_buf / resid_t / h_buf
  s16*   qkv_buf = (s16*)big;
  float* resid_t = (float*)big;
  s16*   h_buf   = (s16*)big;

  dim3 tb(32, 8);
  wtrans<<<dim3(QKVN/32, DM/32), tb, 0, stream>>>(tqkv_w,  wt_tqkv,  DM, QKVN);
  wtrans<<<dim3(DM/32,   DM/32), tb, 0, stream>>>(tproj_w, wt_tproj, DM, DM);
  wtrans<<<dim3(QKVN/32, DM/32), tb, 0, stream>>>(aqkv_w,  wt_aqkv,  DM, QKVN);
  wtrans<<<dim3(DM/32,   DM/32), tb, 0, stream>>>(aproj_w, wt_aproj, DM, DM);
  wtrans<<<dim3(FCN/32,  DM/32), tb, 0, stream>>>(fc1_w,   wt_fc1,   DM, FCN);
  wtrans<<<dim3(DM/32,  FCN/32), tb, 0, stream>>>(fc2_w,   wt_fc2,   FCN, DM);

  const int XT_QKV = QKVN / 256, XT_FC1 = FCN / 256;

  // ---- time branch ----
  ln_k<<<MROWS, 256, 0, stream>>>(x, n3g, n3b, ln_out);
  gemm256<0><<<XT_QKV * MT, 512, 0, stream>>>(ln_out, wt_tqkv, tqkv_b, nullptr, qkv_buf, DM, QKVN, XT_QKV);
  cls_attn<<<BB*NH, 256, 0, stream>>>(qkv_buf, attnout);
  time_attn<<<(BB*NH*NP)/4, 256, 0, stream>>>(qkv_buf, attnout);
  gemm128<2><<<dim3(DM/128, MPAD/128), 256, 0, stream>>>(attnout, wt_tproj, tproj_b, x, resid_t, DM, DM);

  // ---- space branch ----
  ln_k<<<MROWS, 256, 0, stream>>>(resid_t, n1g, n1b, ln_out);
  gemm256<0><<<XT_QKV * MT, 512, 0, stream>>>(ln_out, wt_aqkv, aqkv_b, nullptr, qkv_buf, DM, QKVN, XT_QKV);
  cls_attn<<<BB*NH, 256, 0, stream>>>(qkv_buf, attnout);
  space_attn_mfma<<<BB*NH*FF, 256, 0, stream>>>(qkv_buf, attnout);
  gemm128<2><<<dim3(DM/128, MPAD/128), 256, 0, stream>>>(attnout, wt_aproj, aproj_b, x, resid_s, DM, DM);

  // ---- MLP ----
  ln_k<<<MROWS, 256, 0, stream>>>(resid_s, n2g, n2b, ln_out);
  gemm256<1><<<XT_FC1 * MT, 512, 0, stream>>>(ln_out, wt_fc1, fc1_b, nullptr, h_buf, DM, FCN, XT_FC1);
  gemm128<2><<<dim3(DM/128, MPAD/128), 256, 0, stream>>>(h_buf, wt_fc2, fc2_b, resid_s, out, FCN, DM);
}

// Round 5
// 900.423 us; speedup vs baseline: 1.1497x; 1.0822x over previous
//
#include <hip/hip_runtime.h>
#include <hip/hip_bf16.h>
#include <math.h>

// ---------------- problem constants (from setup_inputs) ----------------
#define DM    768           // model dim
#define NH    12            // heads
#define HD    64            // head dim
#define BB    8             // batch
#define FF    8             // frames
#define NP    196           // spatial positions
#define NT    1569          // 1 + FF*NP tokens
#define MROWS 12552         // BB*NT
#define MPAD  12672         // buffer row padding (99*128)
#define QKVN  2304          // 3*DM
#define FCN   3072          // 4*DM

typedef short s16;          // bf16 stored as raw 16-bit
typedef __attribute__((ext_vector_type(8))) short short8;
typedef __attribute__((ext_vector_type(4))) float floatx4;

__device__ __forceinline__ float bf2f(s16 s) {
  union { unsigned u; float f; } x;
  x.u = ((unsigned)(unsigned short)s) << 16;
  return x.f;
}
__device__ __forceinline__ s16 f2bf(float f) {
  __hip_bfloat16 h = __float2bfloat16(f);
  s16 r;
  __builtin_memcpy(&r, &h, sizeof(r));
  return r;
}
__device__ __forceinline__ void gload16(const void* g, void* l) {
  __builtin_amdgcn_global_load_lds(
      (__attribute__((address_space(1))) void*)g,
      (__attribute__((address_space(3))) void*)l, 16, 0, 0);
}

// ---------------- weight transpose + fp32->bf16 convert ----------------
__global__ void wtrans(const float* __restrict__ W, s16* __restrict__ Wt,
                       int K, int Nn) {
  __shared__ float t[32][33];
  int n0 = blockIdx.x * 32, k0 = blockIdx.y * 32;
  int tx = threadIdx.x, ty = threadIdx.y;   // (32,8)
#pragma unroll
  for (int i = 0; i < 4; ++i)
    t[ty + 8*i][tx] = W[(size_t)(k0 + ty + 8*i) * Nn + n0 + tx];
  __syncthreads();
#pragma unroll
  for (int i = 0; i < 4; ++i)
    Wt[(size_t)(n0 + ty + 8*i) * K + k0 + tx] = f2bf(t[tx][ty + 8*i]);
}

// ---------------- LayerNorm fp32 -> bf16 ----------------
__global__ __launch_bounds__(256) void ln_k(const float* __restrict__ in,
                                            const float* __restrict__ g,
                                            const float* __restrict__ b,
                                            s16* __restrict__ out) {
  __shared__ float red[8];
  int row = blockIdx.x;
  int tid = threadIdx.x;
  const float* rp = in + (size_t)row * DM;
  float v0 = rp[tid], v1 = rp[tid + 256], v2 = rp[tid + 512];
  float s = v0 + v1 + v2;
#pragma unroll
  for (int o = 32; o; o >>= 1) s += __shfl_down(s, o);
  if ((tid & 63) == 0) red[tid >> 6] = s;
  __syncthreads();
  float mean = (red[0] + red[1] + red[2] + red[3]) * (1.0f / DM);
  __syncthreads();
  float d0 = v0 - mean, d1 = v1 - mean, d2 = v2 - mean;
  float q = d0*d0 + d1*d1 + d2*d2;
#pragma unroll
  for (int o = 32; o; o >>= 1) q += __shfl_down(q, o);
  if ((tid & 63) == 0) red[tid >> 6] = q;
  __syncthreads();
  float var = (red[0] + red[1] + red[2] + red[3]) * (1.0f / DM);
  float rs = rsqrtf(var + 1e-5f);
  s16* op = out + (size_t)row * DM;
  op[tid      ] = f2bf(d0 * rs * g[tid      ] + b[tid      ]);
  op[tid + 256] = f2bf(d1 * rs * g[tid + 256] + b[tid + 256]);
  op[tid + 512] = f2bf(d2 * rs * g[tid + 512] + b[tid + 512]);
}

// ---------------- 128x128 2-phase BK=64 bf16 MFMA GEMM ----------------
// Proven structure (R2 base + BK=64): two [128][32] buffer pairs per operand,
// conflict-free reads, 32 KiB LDS -> 3 blocks/CU; implicit cross-block overlap
// (m114) hides the vmcnt drain at __syncthreads. 4 waves, 2x2 wave grid.
// EPI: 0 = bias->bf16 ; 1 = bias+GELU(exact)->bf16 ; 2 = bias+resid->fp32
template<int EPI>
__global__ __launch_bounds__(256) void gemm128(const s16* __restrict__ A,
                                               const s16* __restrict__ Bt,
                                               const float* __restrict__ bias,
                                               const float* __restrict__ resid,
                                               void* __restrict__ out,
                                               int K, int Nn) {
  __shared__ s16 As0[128 * 32], As1[128 * 32];
  __shared__ s16 Bs0[128 * 32], Bs1[128 * 32];
  const int tid = threadIdx.x;
  const int wave = tid >> 6, lane = tid & 63;
  const int row0 = blockIdx.y * 128, col0 = blockIdx.x * 128;
  const int wr = wave >> 1, wc = wave & 1;
  const int lrow = lane & 15, lk = (lane >> 4) * 8;

  floatx4 acc[4][4] = {};

  for (int k0 = 0; k0 < K; k0 += 64) {
#pragma unroll
    for (int i = 0; i < 2; ++i) {
      int elem = ((i * 4 + wave) << 9) + (lane << 3);   // [128][32] linear
      int r = elem >> 5, c = elem & 31;
      const s16* Ap = A  + (size_t)(row0 + r) * K + k0 + c;
      const s16* Bp = Bt + (size_t)(col0 + r) * K + k0 + c;
      gload16(Ap,      As0 + elem);
      gload16(Ap + 32, As1 + elem);
      gload16(Bp,      Bs0 + elem);
      gload16(Bp + 32, Bs1 + elem);
    }
    __syncthreads();
    short8 af0[4], af1[4], bf0[4], bf1[4];
#pragma unroll
    for (int mi = 0; mi < 4; ++mi) {
      int ro = ((wr * 64 + mi * 16 + lrow) << 5) + lk;
      af0[mi] = *reinterpret_cast<const short8*>(As0 + ro);
      af1[mi] = *reinterpret_cast<const short8*>(As1 + ro);
    }
#pragma unroll
    for (int ni = 0; ni < 4; ++ni) {
      int ro = ((wc * 64 + ni * 16 + lrow) << 5) + lk;
      bf0[ni] = *reinterpret_cast<const short8*>(Bs0 + ro);
      bf1[ni] = *reinterpret_cast<const short8*>(Bs1 + ro);
    }
#pragma unroll
    for (int mi = 0; mi < 4; ++mi)
#pragma unroll
      for (int ni = 0; ni < 4; ++ni) {
        acc[mi][ni] = __builtin_amdgcn_mfma_f32_16x16x32_bf16(af0[mi], bf0[ni], acc[mi][ni], 0, 0, 0);
        acc[mi][ni] = __builtin_amdgcn_mfma_f32_16x16x32_bf16(af1[mi], bf1[ni], acc[mi][ni], 0, 0, 0);
      }
    __syncthreads();
  }

  const int c_lane = lane & 15, r_lane = lane >> 4;
#pragma unroll
  for (int mi = 0; mi < 4; ++mi) {
#pragma unroll
    for (int j = 0; j < 4; ++j) {
      int r = row0 + wr * 64 + mi * 16 + r_lane * 4 + j;
      if (r >= MROWS) continue;
#pragma unroll
      for (int ni = 0; ni < 4; ++ni) {
        int c = col0 + wc * 64 + ni * 16 + c_lane;
        float v = acc[mi][ni][j] + bias[c];
        size_t idx = (size_t)r * Nn + c;
        if (EPI == 0) {
          ((s16*)out)[idx] = f2bf(v);
        } else if (EPI == 1) {
          float ge = 0.5f * v * (1.0f + erff(v * 0.70710678118654752f));
          ((s16*)out)[idx] = f2bf(ge);
        } else {
          ((float*)out)[idx] = resid[idx] + v;
        }
      }
    }
  }
}

// ---------------- cls-token attention: 1 query over all NT keys ----------------
__global__ __launch_bounds__(256) void cls_attn(const s16* __restrict__ qkv,
                                                s16* __restrict__ aout) {
  __shared__ float qs[64];
  __shared__ float sc[NT];
  __shared__ float pacc[4][64];
  __shared__ float red[8];
  int bh = blockIdx.x; int b = bh / NH, h = bh % NH;
  int tid = threadIdx.x;
  if (tid < 64) qs[tid] = 0.125f * bf2f(qkv[(size_t)(b*NT) * QKVN + h*HD + tid]);
  __syncthreads();
  for (int t = tid; t < NT; t += 256) {
    const s16* kp = qkv + (size_t)(b*NT + t) * QKVN + DM + h*HD;
    float dot = 0.f;
#pragma unroll
    for (int d8 = 0; d8 < 8; ++d8) {
      short8 kv = *reinterpret_cast<const short8*>(kp + d8*8);
#pragma unroll
      for (int j = 0; j < 8; ++j) dot += qs[d8*8 + j] * bf2f(kv[j]);
    }
    sc[t] = dot;
  }
  __syncthreads();
  float m = -1e30f;
  for (int t = tid; t < NT; t += 256) m = fmaxf(m, sc[t]);
#pragma unroll
  for (int o = 32; o; o >>= 1) m = fmaxf(m, __shfl_xor(m, o));
  if ((tid & 63) == 0) red[tid >> 6] = m;
  __syncthreads();
  m = fmaxf(fmaxf(red[0], red[1]), fmaxf(red[2], red[3]));
  __syncthreads();
  float s = 0.f;
  for (int t = tid; t < NT; t += 256) { float e = expf(sc[t] - m); sc[t] = e; s += e; }
#pragma unroll
  for (int o = 32; o; o >>= 1) s += __shfl_xor(s, o);
  if ((tid & 63) == 0) red[tid >> 6] = s;
  __syncthreads();
  float inv = 1.0f / (red[0] + red[1] + red[2] + red[3]);
  int d = tid & 63, part = tid >> 6;
  float a = 0.f;
  for (int t = part; t < NT; t += 4)
    a += sc[t] * bf2f(qkv[(size_t)(b*NT + t) * QKVN + 2*DM + h*HD + d]);
  pacc[part][d] = a;
  __syncthreads();
  if (tid < 64) {
    float o = (pacc[0][tid] + pacc[1][tid] + pacc[2][tid] + pacc[3][tid]) * inv;
    aout[(size_t)(b*NT) * DM + h*HD + tid] = f2bf(o);
  }
}

// ---------------- time attention: group=(b,h,p), 8 queries x 9 keys ----------------
__global__ __launch_bounds__(256) void time_attn(const s16* __restrict__ qkv,
                                                 s16* __restrict__ aout) {
  int g = blockIdx.x * 4 + (threadIdx.x >> 6);
  int lane = threadIdx.x & 63;
  int p = g % NP; int bh = g / NP; int b = bh / NH, h = bh % NH;
  int qi = lane >> 3;
  int dc = (lane & 7) * 8;
  int tokq = 1 + qi*NP + p;
  short8 qv = *reinterpret_cast<const short8*>(qkv + (size_t)(b*NT + tokq)*QKVN + h*HD + dc);
  float qf[8];
#pragma unroll
  for (int j = 0; j < 8; ++j) qf[j] = 0.125f * bf2f(qv[j]);
  float s[9];
#pragma unroll
  for (int kj = 0; kj < 9; ++kj) {
    int tok = (kj == 0) ? 0 : (1 + (kj - 1)*NP + p);
    short8 kv = *reinterpret_cast<const short8*>(qkv + (size_t)(b*NT + tok)*QKVN + DM + h*HD + dc);
    float d = 0.f;
#pragma unroll
    for (int j = 0; j < 8; ++j) d += qf[j] * bf2f(kv[j]);
    d += __shfl_xor(d, 1); d += __shfl_xor(d, 2); d += __shfl_xor(d, 4);
    s[kj] = d;
  }
  float m = s[0];
#pragma unroll
  for (int kj = 1; kj < 9; ++kj) m = fmaxf(m, s[kj]);
  float sum = 0.f;
#pragma unroll
  for (int kj = 0; kj < 9; ++kj) { s[kj] = expf(s[kj] - m); sum += s[kj]; }
  float inv = 1.0f / sum;
  float o[8] = {0,0,0,0,0,0,0,0};
#pragma unroll
  for (int kj = 0; kj < 9; ++kj) {
    int tok = (kj == 0) ? 0 : (1 + (kj - 1)*NP + p);
    short8 vv = *reinterpret_cast<const short8*>(qkv + (size_t)(b*NT + tok)*QKVN + 2*DM + h*HD + dc);
#pragma unroll
    for (int j = 0; j < 8; ++j) o[j] += s[kj] * bf2f(vv[j]);
  }
  short8 ov;
#pragma unroll
  for (int j = 0; j < 8; ++j) ov[j] = f2bf(o[j] * inv);
  *reinterpret_cast<short8*>(aout + (size_t)(b*NT + tokq)*DM + h*HD + dc) = ov;
}

// ---------------- space attention (MFMA): group=(b,h,frame), 196 q x 197 k ----------------
#define PST 232
#define VST 232
__global__ __launch_bounds__(256) void space_attn_mfma(const s16* __restrict__ qkv,
                                                       s16* __restrict__ aout) {
  __shared__ s16 Vt[64][VST];
  __shared__ s16 P[4][16][PST];
  int grp = blockIdx.x;
  int fr = grp & 7; int bh = grp >> 3; int b = bh / NH, h = bh % NH;
  int tid = threadIdx.x, w = tid >> 6, lane = tid & 63;
  const size_t hbase = (size_t)(b * NT) * QKVN + h * HD;

  for (int idx = tid; idx < 224 * 8; idx += 256) {
    int kj = idx >> 3, c8 = idx & 7;
    if (kj < 197) {
      int tok = (kj == 0) ? 0 : (1 + fr * NP + kj - 1);
      short8 vv = *reinterpret_cast<const short8*>(qkv + hbase + (size_t)tok * QKVN + 2 * DM + c8 * 8);
#pragma unroll
      for (int j = 0; j < 8; ++j) Vt[c8 * 8 + j][kj] = vv[j];
    } else {
#pragma unroll
      for (int j = 0; j < 8; ++j) Vt[c8 * 8 + j][kj] = 0;
    }
  }
  for (int i = tid; i < 4 * 16 * 16; i += 256) {
    int wv = i >> 8, rr2 = (i >> 4) & 15, cc = i & 15;
    P[wv][rr2][208 + cc] = 0;
  }
  __syncthreads();

  const int lr = lane & 15, lg = lane >> 4;

  for (int t0 = w; t0 < 13; t0 += 4) {
    int q0 = t0 * 16;
    short8 aq[2];
#pragma unroll
    for (int c = 0; c < 2; ++c) {
      int tokq = 1 + fr * NP + q0 + lr;
      aq[c] = *reinterpret_cast<const short8*>(qkv + hbase + (size_t)tokq * QKVN + c * 32 + lg * 8);
    }
    short8 kb[13][2];
#pragma unroll
    for (int t = 0; t < 13; ++t) {
#pragma unroll
      for (int c = 0; c < 2; ++c) {
        int krow = t * 16 + lr;
        int tokk = (krow == 0) ? 0 : (1 + fr * NP + krow - 1);
        kb[t][c] = *reinterpret_cast<const short8*>(qkv + hbase + (size_t)tokk * QKVN + DM + c * 32 + lg * 8);
      }
    }
    floatx4 st[13];
#pragma unroll
    for (int t = 0; t < 13; ++t) st[t] = (floatx4){0.f, 0.f, 0.f, 0.f};
#pragma unroll
    for (int t = 0; t < 13; ++t) {
      st[t] = __builtin_amdgcn_mfma_f32_16x16x32_bf16(aq[0], kb[t][0], st[t], 0, 0, 0);
      st[t] = __builtin_amdgcn_mfma_f32_16x16x32_bf16(aq[1], kb[t][1], st[t], 0, 0, 0);
    }
    float mj[4] = {-1e30f, -1e30f, -1e30f, -1e30f};
#pragma unroll
    for (int t = 0; t < 13; ++t) {
      int key = t * 16 + lr;
#pragma unroll
      for (int j = 0; j < 4; ++j) {
        float v = (key < 197) ? st[t][j] * 0.125f : -1e30f;
        st[t][j] = v;
        mj[j] = fmaxf(mj[j], v);
      }
    }
#pragma unroll
    for (int j = 0; j < 4; ++j) {
      mj[j] = fmaxf(mj[j], __shfl_xor(mj[j], 1));
      mj[j] = fmaxf(mj[j], __shfl_xor(mj[j], 2));
      mj[j] = fmaxf(mj[j], __shfl_xor(mj[j], 4));
      mj[j] = fmaxf(mj[j], __shfl_xor(mj[j], 8));
    }
    float su[4] = {0.f, 0.f, 0.f, 0.f};
#pragma unroll
    for (int t = 0; t < 13; ++t)
#pragma unroll
      for (int j = 0; j < 4; ++j) {
        float e = __expf(st[t][j] - mj[j]);
        st[t][j] = e;
        su[j] += e;
      }
#pragma unroll
    for (int j = 0; j < 4; ++j) {
      su[j] += __shfl_xor(su[j], 1);
      su[j] += __shfl_xor(su[j], 2);
      su[j] += __shfl_xor(su[j], 4);
      su[j] += __shfl_xor(su[j], 8);
    }
    float inv[4];
#pragma unroll
    for (int j = 0; j < 4; ++j) inv[j] = 1.0f / su[j];
#pragma unroll
    for (int t = 0; t < 13; ++t)
#pragma unroll
      for (int j = 0; j < 4; ++j)
        P[w][lg * 4 + j][t * 16 + lr] = f2bf(st[t][j]);
    floatx4 o[4];
#pragma unroll
    for (int dt = 0; dt < 4; ++dt) o[dt] = (floatx4){0.f, 0.f, 0.f, 0.f};
#pragma unroll
    for (int kc = 0; kc < 7; ++kc) {
      short8 pa = *reinterpret_cast<const short8*>(&P[w][lr][kc * 32 + lg * 8]);
#pragma unroll
      for (int dt = 0; dt < 4; ++dt) {
        short8 vb = *reinterpret_cast<const short8*>(&Vt[dt * 16 + lr][kc * 32 + lg * 8]);
        o[dt] = __builtin_amdgcn_mfma_f32_16x16x32_bf16(pa, vb, o[dt], 0, 0, 0);
      }
    }
#pragma unroll
    for (int dt = 0; dt < 4; ++dt)
#pragma unroll
      for (int j = 0; j < 4; ++j) {
        int q = q0 + lg * 4 + j;
        if (q < NP) {
          int tokq = 1 + fr * NP + q;
          aout[(size_t)(b * NT + tokq) * DM + h * HD + dt * 16 + lr] = f2bf(o[dt][j] * inv[j]);
        }
      }
  }
}

// ---------------- host launcher ----------------
extern "C" void kernel_launch(void* const* d_in, const int* in_sizes, int n_in,
                              void* d_out, int out_size, void* d_ws, size_t ws_size,
                              hipStream_t stream) {
  const float* x       = (const float*)d_in[0];
  const float* n1g     = (const float*)d_in[1];
  const float* n1b     = (const float*)d_in[2];
  const float* n2g     = (const float*)d_in[3];
  const float* n2b     = (const float*)d_in[4];
  const float* n3g     = (const float*)d_in[5];
  const float* n3b     = (const float*)d_in[6];
  const float* aqkv_w  = (const float*)d_in[7];
  const float* aqkv_b  = (const float*)d_in[8];
  const float* aproj_w = (const float*)d_in[9];
  const float* aproj_b = (const float*)d_in[10];
  const float* tqkv_w  = (const float*)d_in[11];
  const float* tqkv_b  = (const float*)d_in[12];
  const float* tproj_w = (const float*)d_in[13];
  const float* tproj_b = (const float*)d_in[14];
  const float* fc1_w   = (const float*)d_in[15];
  const float* fc1_b   = (const float*)d_in[16];
  const float* fc2_w   = (const float*)d_in[17];
  const float* fc2_b   = (const float*)d_in[18];
  float* out = (float*)d_out;

  char* ws = (char*)d_ws;
  size_t off = 0;
  auto alloc = [&](size_t bytes) -> void* {
    void* p = ws + off;
    off += (bytes + 255) & ~(size_t)255;
    return p;
  };
  s16*  wt_tqkv  = (s16*)alloc((size_t)QKVN * DM * 2);
  s16*  wt_tproj = (s16*)alloc((size_t)DM * DM * 2);
  s16*  wt_aqkv  = (s16*)alloc((size_t)QKVN * DM * 2);
  s16*  wt_aproj = (s16*)alloc((size_t)DM * DM * 2);
  s16*  wt_fc1   = (s16*)alloc((size_t)FCN * DM * 2);
  s16*  wt_fc2   = (s16*)alloc((size_t)DM * FCN * 2);
  s16*  ln_out   = (s16*)alloc((size_t)MPAD * DM * 2);
  s16*  attnout  = (s16*)alloc((size_t)MPAD * DM * 2);
  float* resid_s = (float*)alloc((size_t)MROWS * DM * 4);
  char* big      = (char*)alloc((size_t)MPAD * FCN * 2);  // union: qkv_buf / resid_t / h_buf
  s16*   qkv_buf = (s16*)big;
  float* resid_t = (float*)big;
  s16*   h_buf   = (s16*)big;

  dim3 tb(32, 8);
  wtrans<<<dim3(QKVN/32, DM/32), tb, 0, stream>>>(tqkv_w,  wt_tqkv,  DM, QKVN);
  wtrans<<<dim3(DM/32,   DM/32), tb, 0, stream>>>(tproj_w, wt_tproj, DM, DM);
  wtrans<<<dim3(QKVN/32, DM/32), tb, 0, stream>>>(aqkv_w,  wt_aqkv,  DM, QKVN);
  wtrans<<<dim3(DM/32,   DM/32), tb, 0, stream>>>(aproj_w, wt_aproj, DM, DM);
  wtrans<<<dim3(FCN/32,  DM/32), tb, 0, stream>>>(fc1_w,   wt_fc1,   DM, FCN);
  wtrans<<<dim3(DM/32,  FCN/32), tb, 0, stream>>>(fc2_w,   wt_fc2,   FCN, DM);

  // ---- time branch ----
  ln_k<<<MROWS, 256, 0, stream>>>(x, n3g, n3b, ln_out);
  gemm128<0><<<dim3(QKVN/128, MPAD/128), 256, 0, stream>>>(ln_out, wt_tqkv, tqkv_b, nullptr, qkv_buf, DM, QKVN);
  cls_attn<<<BB*NH, 256, 0, stream>>>(qkv_buf, attnout);
  time_attn<<<(BB*NH*NP)/4, 256, 0, stream>>>(qkv_buf, attnout);
  gemm128<2><<<dim3(DM/128, MPAD/128), 256, 0, stream>>>(attnout, wt_tproj, tproj_b, x, resid_t, DM, DM);

  // ---- space branch ----
  ln_k<<<MROWS, 256, 0, stream>>>(resid_t, n1g, n1b, ln_out);
  gemm128<0><<<dim3(QKVN/128, MPAD/128), 256, 0, stream>>>(ln_out, wt_aqkv, aqkv_b, nullptr, qkv_buf, DM, QKVN);
  cls_attn<<<BB*NH, 256, 0, stream>>>(qkv_buf, attnout);
  space_attn_mfma<<<BB*NH*FF, 256, 0, stream>>>(qkv_buf, attnout);
  gemm128<2><<<dim3(DM/128, MPAD/128), 256, 0, stream>>>(attnout, wt_aproj, aproj_b, x, resid_s, DM, DM);

  // ---- MLP ----
  ln_k<<<MROWS, 256, 0, stream>>>(resid_s, n2g, n2b, ln_out);
  gemm128<1><<<dim3(FCN/128, MPAD/128), 256, 0, stream>>>(ln_out, wt_fc1, fc1_b, nullptr, h_buf, DM, FCN);
  gemm128<2><<<dim3(DM/128, MPAD/128), 256, 0, stream>>>(h_buf, wt_fc2, fc2_b, resid_s, out, FCN, DM);
}

// Round 6
// 651.522 us; speedup vs baseline: 1.5889x; 1.3820x over previous
//
#include <hip/hip_runtime.h>
#include <hip/hip_bf16.h>
#include <math.h>

// ---------------- problem constants (from setup_inputs) ----------------
#define DM    768           // model dim
#define NH    12            // heads
#define HD    64            // head dim
#define BB    8             // batch
#define FF    8             // frames
#define NP    196           // spatial positions
#define NT    1569          // 1 + FF*NP tokens
#define MROWS 12552         // BB*NT
#define MPAD  12672         // buffer row padding (99*128)
#define YT    99            // MPAD/128 row tiles
#define QKVN  2304          // 3*DM
#define FCN   3072          // 4*DM
#define CHK   197           // cls split: keys per chunk (8*197=1576>=1569)

typedef short s16;          // bf16 stored as raw 16-bit
typedef __attribute__((ext_vector_type(8))) short short8;
typedef __attribute__((ext_vector_type(4))) float floatx4;

__device__ __forceinline__ float bf2f(s16 s) {
  union { unsigned u; float f; } x;
  x.u = ((unsigned)(unsigned short)s) << 16;
  return x.f;
}
__device__ __forceinline__ s16 f2bf(float f) {
  __hip_bfloat16 h = __float2bfloat16(f);
  s16 r;
  __builtin_memcpy(&r, &h, sizeof(r));
  return r;
}
__device__ __forceinline__ void gload16(const void* g, void* l) {
  __builtin_amdgcn_global_load_lds(
      (__attribute__((address_space(1))) void*)g,
      (__attribute__((address_space(3))) void*)l, 16, 0, 0);
}

// ---------------- weight transpose + fp32->bf16 convert ----------------
__global__ void wtrans(const float* __restrict__ W, s16* __restrict__ Wt,
                       int K, int Nn) {
  __shared__ float t[32][33];
  int n0 = blockIdx.x * 32, k0 = blockIdx.y * 32;
  int tx = threadIdx.x, ty = threadIdx.y;   // (32,8)
#pragma unroll
  for (int i = 0; i < 4; ++i)
    t[ty + 8*i][tx] = W[(size_t)(k0 + ty + 8*i) * Nn + n0 + tx];
  __syncthreads();
#pragma unroll
  for (int i = 0; i < 4; ++i)
    Wt[(size_t)(n0 + ty + 8*i) * K + k0 + tx] = f2bf(t[tx][ty + 8*i]);
}

// ---------------- LayerNorm fp32 -> bf16 ----------------
__global__ __launch_bounds__(256) void ln_k(const float* __restrict__ in,
                                            const float* __restrict__ g,
                                            const float* __restrict__ b,
                                            s16* __restrict__ out) {
  __shared__ float red[8];
  int row = blockIdx.x;
  int tid = threadIdx.x;
  const float* rp = in + (size_t)row * DM;
  float v0 = rp[tid], v1 = rp[tid + 256], v2 = rp[tid + 512];
  float s = v0 + v1 + v2;
#pragma unroll
  for (int o = 32; o; o >>= 1) s += __shfl_down(s, o);
  if ((tid & 63) == 0) red[tid >> 6] = s;
  __syncthreads();
  float mean = (red[0] + red[1] + red[2] + red[3]) * (1.0f / DM);
  __syncthreads();
  float d0 = v0 - mean, d1 = v1 - mean, d2 = v2 - mean;
  float q = d0*d0 + d1*d1 + d2*d2;
#pragma unroll
  for (int o = 32; o; o >>= 1) q += __shfl_down(q, o);
  if ((tid & 63) == 0) red[tid >> 6] = q;
  __syncthreads();
  float var = (red[0] + red[1] + red[2] + red[3]) * (1.0f / DM);
  float rs = rsqrtf(var + 1e-5f);
  s16* op = out + (size_t)row * DM;
  op[tid      ] = f2bf(d0 * rs * g[tid      ] + b[tid      ]);
  op[tid + 256] = f2bf(d1 * rs * g[tid + 256] + b[tid + 256]);
  op[tid + 512] = f2bf(d2 * rs * g[tid + 512] + b[tid + 512]);
}

// ---------------- 128x128 2-phase BK=64 bf16 MFMA GEMM ----------------
// Proven structure (R5) + T1 XCD-chunked bijective swizzle (m204) + 3-blocks/CU
// occupancy hint. Two [128][32] buffer pairs per operand, conflict pattern
// untouched (T2 null at 2ph). 4 waves, 2x2 wave grid.
// EPI: 0 = bias->bf16 ; 1 = bias+GELU(exact)->bf16 ; 2 = bias+resid->fp32
template<int EPI>
__global__ __launch_bounds__(256, 3) void gemm128(const s16* __restrict__ A,
                                                  const s16* __restrict__ Bt,
                                                  const float* __restrict__ bias,
                                                  const float* __restrict__ resid,
                                                  void* __restrict__ out,
                                                  int K, int Nn, int xt) {
  __shared__ s16 As0[128 * 32], As1[128 * 32];
  __shared__ s16 Bs0[128 * 32], Bs1[128 * 32];
  // bijective XCD swizzle: each XCD gets a contiguous wgid chunk; within a
  // chunk bx iterates fastest -> same A row-panel stays on one XCD's L2.
  const int nwg = gridDim.x, orig = blockIdx.x;
  const int qq = nwg >> 3, rr = nwg & 7, xcd = orig & 7, lid = orig >> 3;
  const int wgid = (xcd < rr ? xcd * (qq + 1) : rr * (qq + 1) + (xcd - rr) * qq) + lid;
  const int row0 = (wgid / xt) * 128, col0 = (wgid % xt) * 128;
  const int tid = threadIdx.x;
  const int wave = tid >> 6, lane = tid & 63;
  const int wr = wave >> 1, wc = wave & 1;
  const int lrow = lane & 15, lk = (lane >> 4) * 8;

  floatx4 acc[4][4] = {};

  for (int k0 = 0; k0 < K; k0 += 64) {
#pragma unroll
    for (int i = 0; i < 2; ++i) {
      int elem = ((i * 4 + wave) << 9) + (lane << 3);   // [128][32] linear
      int r = elem >> 5, c = elem & 31;
      const s16* Ap = A  + (size_t)(row0 + r) * K + k0 + c;
      const s16* Bp = Bt + (size_t)(col0 + r) * K + k0 + c;
      gload16(Ap,      As0 + elem);
      gload16(Ap + 32, As1 + elem);
      gload16(Bp,      Bs0 + elem);
      gload16(Bp + 32, Bs1 + elem);
    }
    __syncthreads();
    short8 af0[4], af1[4], bf0[4], bf1[4];
#pragma unroll
    for (int mi = 0; mi < 4; ++mi) {
      int ro = ((wr * 64 + mi * 16 + lrow) << 5) + lk;
      af0[mi] = *reinterpret_cast<const short8*>(As0 + ro);
      af1[mi] = *reinterpret_cast<const short8*>(As1 + ro);
    }
#pragma unroll
    for (int ni = 0; ni < 4; ++ni) {
      int ro = ((wc * 64 + ni * 16 + lrow) << 5) + lk;
      bf0[ni] = *reinterpret_cast<const short8*>(Bs0 + ro);
      bf1[ni] = *reinterpret_cast<const short8*>(Bs1 + ro);
    }
#pragma unroll
    for (int mi = 0; mi < 4; ++mi)
#pragma unroll
      for (int ni = 0; ni < 4; ++ni) {
        acc[mi][ni] = __builtin_amdgcn_mfma_f32_16x16x32_bf16(af0[mi], bf0[ni], acc[mi][ni], 0, 0, 0);
        acc[mi][ni] = __builtin_amdgcn_mfma_f32_16x16x32_bf16(af1[mi], bf1[ni], acc[mi][ni], 0, 0, 0);
      }
    __syncthreads();
  }

  const int c_lane = lane & 15, r_lane = lane >> 4;
#pragma unroll
  for (int mi = 0; mi < 4; ++mi) {
#pragma unroll
    for (int j = 0; j < 4; ++j) {
      int r = row0 + wr * 64 + mi * 16 + r_lane * 4 + j;
      if (r >= MROWS) continue;
#pragma unroll
      for (int ni = 0; ni < 4; ++ni) {
        int c = col0 + wc * 64 + ni * 16 + c_lane;
        float v = acc[mi][ni][j] + bias[c];
        size_t idx = (size_t)r * Nn + c;
        if (EPI == 0) {
          ((s16*)out)[idx] = f2bf(v);
        } else if (EPI == 1) {
          float ge = 0.5f * v * (1.0f + erff(v * 0.70710678118654752f));
          ((s16*)out)[idx] = f2bf(ge);
        } else {
          ((float*)out)[idx] = resid[idx] + v;
        }
      }
    }
  }
}

// ---------------- cls attention, pass 1: per-(b,h,chunk) partials ----------------
// block = bh*8 + chunk; chunk covers keys [ch*CHK, min(NT,(ch+1)*CHK)).
// Writes part[blk] = {m_local, s_local, acc[64]} (stride 66 floats).
__global__ __launch_bounds__(256) void cls_part(const s16* __restrict__ qkv,
                                                float* __restrict__ part) {
  __shared__ float qs[64];
  __shared__ float sc[CHK];
  __shared__ float pacc[4][64];
  __shared__ float red[8];
  int blk = blockIdx.x; int ch = blk & 7; int bh = blk >> 3;
  int b = bh / NH, h = bh % NH;
  int tid = threadIdx.x;
  int t0 = ch * CHK;
  int nk = NT - t0; if (nk > CHK) nk = CHK;
  if (tid < 64) qs[tid] = 0.125f * bf2f(qkv[(size_t)(b*NT) * QKVN + h*HD + tid]);
  __syncthreads();
  for (int i = tid; i < nk; i += 256) {
    const s16* kp = qkv + (size_t)(b*NT + t0 + i) * QKVN + DM + h*HD;
    float dot = 0.f;
#pragma unroll
    for (int d8 = 0; d8 < 8; ++d8) {
      short8 kv = *reinterpret_cast<const short8*>(kp + d8*8);
#pragma unroll
      for (int j = 0; j < 8; ++j) dot += qs[d8*8 + j] * bf2f(kv[j]);
    }
    sc[i] = dot;
  }
  __syncthreads();
  float m = -1e30f;
  for (int i = tid; i < nk; i += 256) m = fmaxf(m, sc[i]);
#pragma unroll
  for (int o = 32; o; o >>= 1) m = fmaxf(m, __shfl_xor(m, o));
  if ((tid & 63) == 0) red[tid >> 6] = m;
  __syncthreads();
  m = fmaxf(fmaxf(red[0], red[1]), fmaxf(red[2], red[3]));
  __syncthreads();
  float s = 0.f;
  for (int i = tid; i < nk; i += 256) { float e = __expf(sc[i] - m); sc[i] = e; s += e; }
#pragma unroll
  for (int o = 32; o; o >>= 1) s += __shfl_xor(s, o);
  if ((tid & 63) == 0) red[tid >> 6] = s;
  __syncthreads();
  float S = red[0] + red[1] + red[2] + red[3];
  int d = tid & 63, pt = tid >> 6;
  float a = 0.f;
  for (int i = pt; i < nk; i += 4)
    a += sc[i] * bf2f(qkv[(size_t)(b*NT + t0 + i) * QKVN + 2*DM + h*HD + d]);
  pacc[pt][d] = a;
  __syncthreads();
  float* pp = part + (size_t)blk * 66;
  if (tid < 64) pp[2 + tid] = pacc[0][tid] + pacc[1][tid] + pacc[2][tid] + pacc[3][tid];
  if (tid == 0) { pp[0] = m; pp[1] = S; }
}

// ---------------- cls attention, pass 2: merge 8 chunks per (b,h) ----------------
__global__ __launch_bounds__(64) void cls_combine(const float* __restrict__ part,
                                                  s16* __restrict__ aout) {
  int bh = blockIdx.x; int b = bh / NH, h = bh % NH;
  int d = threadIdx.x;
  float m = -1e30f;
#pragma unroll
  for (int c = 0; c < 8; ++c) m = fmaxf(m, part[(size_t)(bh*8 + c) * 66]);
  float S = 0.f, A = 0.f;
#pragma unroll
  for (int c = 0; c < 8; ++c) {
    const float* pp = part + (size_t)(bh*8 + c) * 66;
    float w = __expf(pp[0] - m);
    S += pp[1] * w;
    A += w * pp[2 + d];
  }
  aout[(size_t)(b*NT) * DM + h*HD + d] = f2bf(A / S);
}

// ---------------- time attention: group=(b,h,p), 8 queries x 9 keys ----------------
__global__ __launch_bounds__(256) void time_attn(const s16* __restrict__ qkv,
                                                 s16* __restrict__ aout) {
  int g = blockIdx.x * 4 + (threadIdx.x >> 6);
  int lane = threadIdx.x & 63;
  int p = g % NP; int bh = g / NP; int b = bh / NH, h = bh % NH;
  int qi = lane >> 3;
  int dc = (lane & 7) * 8;
  int tokq = 1 + qi*NP + p;
  short8 qv = *reinterpret_cast<const short8*>(qkv + (size_t)(b*NT + tokq)*QKVN + h*HD + dc);
  float qf[8];
#pragma unroll
  for (int j = 0; j < 8; ++j) qf[j] = 0.125f * bf2f(qv[j]);
  float s[9];
#pragma unroll
  for (int kj = 0; kj < 9; ++kj) {
    int tok = (kj == 0) ? 0 : (1 + (kj - 1)*NP + p);
    short8 kv = *reinterpret_cast<const short8*>(qkv + (size_t)(b*NT + tok)*QKVN + DM + h*HD + dc);
    float d = 0.f;
#pragma unroll
    for (int j = 0; j < 8; ++j) d += qf[j] * bf2f(kv[j]);
    d += __shfl_xor(d, 1); d += __shfl_xor(d, 2); d += __shfl_xor(d, 4);
    s[kj] = d;
  }
  float m = s[0];
#pragma unroll
  for (int kj = 1; kj < 9; ++kj) m = fmaxf(m, s[kj]);
  float sum = 0.f;
#pragma unroll
  for (int kj = 0; kj < 9; ++kj) { s[kj] = expf(s[kj] - m); sum += s[kj]; }
  float inv = 1.0f / sum;
  float o[8] = {0,0,0,0,0,0,0,0};
#pragma unroll
  for (int kj = 0; kj < 9; ++kj) {
    int tok = (kj == 0) ? 0 : (1 + (kj - 1)*NP + p);
    short8 vv = *reinterpret_cast<const short8*>(qkv + (size_t)(b*NT + tok)*QKVN + 2*DM + h*HD + dc);
#pragma unroll
    for (int j = 0; j < 8; ++j) o[j] += s[kj] * bf2f(vv[j]);
  }
  short8 ov;
#pragma unroll
  for (int j = 0; j < 8; ++j) ov[j] = f2bf(o[j] * inv);
  *reinterpret_cast<short8*>(aout + (size_t)(b*NT + tokq)*DM + h*HD + dc) = ov;
}

// ---------------- space attention (MFMA): group=(b,h,frame), 196 q x 197 k ----------------
#define PST 232
#define VST 232
__global__ __launch_bounds__(256) void space_attn_mfma(const s16* __restrict__ qkv,
                                                       s16* __restrict__ aout) {
  __shared__ s16 Vt[64][VST];
  __shared__ s16 P[4][16][PST];
  int grp = blockIdx.x;
  int fr = grp & 7; int bh = grp >> 3; int b = bh / NH, h = bh % NH;
  int tid = threadIdx.x, w = tid >> 6, lane = tid & 63;
  const size_t hbase = (size_t)(b * NT) * QKVN + h * HD;

  for (int idx = tid; idx < 224 * 8; idx += 256) {
    int kj = idx >> 3, c8 = idx & 7;
    if (kj < 197) {
      int tok = (kj == 0) ? 0 : (1 + fr * NP + kj - 1);
      short8 vv = *reinterpret_cast<const short8*>(qkv + hbase + (size_t)tok * QKVN + 2 * DM + c8 * 8);
#pragma unroll
      for (int j = 0; j < 8; ++j) Vt[c8 * 8 + j][kj] = vv[j];
    } else {
#pragma unroll
      for (int j = 0; j < 8; ++j) Vt[c8 * 8 + j][kj] = 0;
    }
  }
  for (int i = tid; i < 4 * 16 * 16; i += 256) {
    int wv = i >> 8, rr2 = (i >> 4) & 15, cc = i & 15;
    P[wv][rr2][208 + cc] = 0;
  }
  __syncthreads();

  const int lr = lane & 15, lg = lane >> 4;

  for (int t0 = w; t0 < 13; t0 += 4) {
    int q0 = t0 * 16;
    short8 aq[2];
#pragma unroll
    for (int c = 0; c < 2; ++c) {
      int tokq = 1 + fr * NP + q0 + lr;
      aq[c] = *reinterpret_cast<const short8*>(qkv + hbase + (size_t)tokq * QKVN + c * 32 + lg * 8);
    }
    short8 kb[13][2];
#pragma unroll
    for (int t = 0; t < 13; ++t) {
#pragma unroll
      for (int c = 0; c < 2; ++c) {
        int krow = t * 16 + lr;
        int tokk = (krow == 0) ? 0 : (1 + fr * NP + krow - 1);
        kb[t][c] = *reinterpret_cast<const short8*>(qkv + hbase + (size_t)tokk * QKVN + DM + c * 32 + lg * 8);
      }
    }
    floatx4 st[13];
#pragma unroll
    for (int t = 0; t < 13; ++t) st[t] = (floatx4){0.f, 0.f, 0.f, 0.f};
#pragma unroll
    for (int t = 0; t < 13; ++t) {
      st[t] = __builtin_amdgcn_mfma_f32_16x16x32_bf16(aq[0], kb[t][0], st[t], 0, 0, 0);
      st[t] = __builtin_amdgcn_mfma_f32_16x16x32_bf16(aq[1], kb[t][1], st[t], 0, 0, 0);
    }
    float mj[4] = {-1e30f, -1e30f, -1e30f, -1e30f};
#pragma unroll
    for (int t = 0; t < 13; ++t) {
      int key = t * 16 + lr;
#pragma unroll
      for (int j = 0; j < 4; ++j) {
        float v = (key < 197) ? st[t][j] * 0.125f : -1e30f;
        st[t][j] = v;
        mj[j] = fmaxf(mj[j], v);
      }
    }
#pragma unroll
    for (int j = 0; j < 4; ++j) {
      mj[j] = fmaxf(mj[j], __shfl_xor(mj[j], 1));
      mj[j] = fmaxf(mj[j], __shfl_xor(mj[j], 2));
      mj[j] = fmaxf(mj[j], __shfl_xor(mj[j], 4));
      mj[j] = fmaxf(mj[j], __shfl_xor(mj[j], 8));
    }
    float su[4] = {0.f, 0.f, 0.f, 0.f};
#pragma unroll
    for (int t = 0; t < 13; ++t)
#pragma unroll
      for (int j = 0; j < 4; ++j) {
        float e = __expf(st[t][j] - mj[j]);
        st[t][j] = e;
        su[j] += e;
      }
#pragma unroll
    for (int j = 0; j < 4; ++j) {
      su[j] += __shfl_xor(su[j], 1);
      su[j] += __shfl_xor(su[j], 2);
      su[j] += __shfl_xor(su[j], 4);
      su[j] += __shfl_xor(su[j], 8);
    }
    float inv[4];
#pragma unroll
    for (int j = 0; j < 4; ++j) inv[j] = 1.0f / su[j];
#pragma unroll
    for (int t = 0; t < 13; ++t)
#pragma unroll
      for (int j = 0; j < 4; ++j)
        P[w][lg * 4 + j][t * 16 + lr] = f2bf(st[t][j]);
    floatx4 o[4];
#pragma unroll
    for (int dt = 0; dt < 4; ++dt) o[dt] = (floatx4){0.f, 0.f, 0.f, 0.f};
#pragma unroll
    for (int kc = 0; kc < 7; ++kc) {
      short8 pa = *reinterpret_cast<const short8*>(&P[w][lr][kc * 32 + lg * 8]);
#pragma unroll
      for (int dt = 0; dt < 4; ++dt) {
        short8 vb = *reinterpret_cast<const short8*>(&Vt[dt * 16 + lr][kc * 32 + lg * 8]);
        o[dt] = __builtin_amdgcn_mfma_f32_16x16x32_bf16(pa, vb, o[dt], 0, 0, 0);
      }
    }
#pragma unroll
    for (int dt = 0; dt < 4; ++dt)
#pragma unroll
      for (int j = 0; j < 4; ++j) {
        int q = q0 + lg * 4 + j;
        if (q < NP) {
          int tokq = 1 + fr * NP + q;
          aout[(size_t)(b * NT + tokq) * DM + h * HD + dt * 16 + lr] = f2bf(o[dt][j] * inv[j]);
        }
      }
  }
}

// ---------------- host launcher ----------------
extern "C" void kernel_launch(void* const* d_in, const int* in_sizes, int n_in,
                              void* d_out, int out_size, void* d_ws, size_t ws_size,
                              hipStream_t stream) {
  const float* x       = (const float*)d_in[0];
  const float* n1g     = (const float*)d_in[1];
  const float* n1b     = (const float*)d_in[2];
  const float* n2g     = (const float*)d_in[3];
  const float* n2b     = (const float*)d_in[4];
  const float* n3g     = (const float*)d_in[5];
  const float* n3b     = (const float*)d_in[6];
  const float* aqkv_w  = (const float*)d_in[7];
  const float* aqkv_b  = (const float*)d_in[8];
  const float* aproj_w = (const float*)d_in[9];
  const float* aproj_b = (const float*)d_in[10];
  const float* tqkv_w  = (const float*)d_in[11];
  const float* tqkv_b  = (const float*)d_in[12];
  const float* tproj_w = (const float*)d_in[13];
  const float* tproj_b = (const float*)d_in[14];
  const float* fc1_w   = (const float*)d_in[15];
  const float* fc1_b   = (const float*)d_in[16];
  const float* fc2_w   = (const float*)d_in[17];
  const float* fc2_b   = (const float*)d_in[18];
  float* out = (float*)d_out;

  char* ws = (char*)d_ws;
  size_t off = 0;
  auto alloc = [&](size_t bytes) -> void* {
    void* p = ws + off;
    off += (bytes + 255) & ~(size_t)255;
    return p;
  };
  s16*  wt_tqkv  = (s16*)alloc((size_t)QKVN * DM * 2);
  s16*  wt_tproj = (s16*)alloc((size_t)DM * DM * 2);
  s16*  wt_aqkv  = (s16*)alloc((size_t)QKVN * DM * 2);
  s16*  wt_aproj = (s16*)alloc((size_t)DM * DM * 2);
  s16*  wt_fc1   = (s16*)alloc((size_t)FCN * DM * 2);
  s16*  wt_fc2   = (s16*)alloc((size_t)DM * FCN * 2);
  s16*  ln_out   = (s16*)alloc((size_t)MPAD * DM * 2);
  s16*  attnout  = (s16*)alloc((size_t)MPAD * DM * 2);
  float* resid_s = (float*)alloc((size_t)MROWS * DM * 4);
  float* clspart = (float*)alloc((size_t)BB * NH * 8 * 66 * 4);
  char* big      = (char*)alloc((size_t)MPAD * FCN * 2);  // union: qkv_buf / resid_t / h_buf
  s16*   qkv_buf = (s16*)big;
  float* resid_t = (float*)big;
  s16*   h_buf   = (s16*)big;

  dim3 tb(32, 8);
  wtrans<<<dim3(QKVN/32, DM/32), tb, 0, stream>>>(tqkv_w,  wt_tqkv,  DM, QKVN);
  wtrans<<<dim3(DM/32,   DM/32), tb, 0, stream>>>(tproj_w, wt_tproj, DM, DM);
  wtrans<<<dim3(QKVN/32, DM/32), tb, 0, stream>>>(aqkv_w,  wt_aqkv,  DM, QKVN);
  wtrans<<<dim3(DM/32,   DM/32), tb, 0, stream>>>(aproj_w, wt_aproj, DM, DM);
  wtrans<<<dim3(FCN/32,  DM/32), tb, 0, stream>>>(fc1_w,   wt_fc1,   DM, FCN);
  wtrans<<<dim3(DM/32,  FCN/32), tb, 0, stream>>>(fc2_w,   wt_fc2,   FCN, DM);

  const int XT_QKV = QKVN / 128, XT_PRJ = DM / 128, XT_FC1 = FCN / 128;

  // ---- time branch ----
  ln_k<<<MROWS, 256, 0, stream>>>(x, n3g, n3b, ln_out);
  gemm128<0><<<XT_QKV * YT, 256, 0, stream>>>(ln_out, wt_tqkv, tqkv_b, nullptr, qkv_buf, DM, QKVN, XT_QKV);
  cls_part<<<BB*NH*8, 256, 0, stream>>>(qkv_buf, clspart);
  cls_combine<<<BB*NH, 64, 0, stream>>>(clspart, attnout);
  time_attn<<<(BB*NH*NP)/4, 256, 0, stream>>>(qkv_buf, attnout);
  gemm128<2><<<XT_PRJ * YT, 256, 0, stream>>>(attnout, wt_tproj, tproj_b, x, resid_t, DM, DM, XT_PRJ);

  // ---- space branch ----
  ln_k<<<MROWS, 256, 0, stream>>>(resid_t, n1g, n1b, ln_out);
  gemm128<0><<<XT_QKV * YT, 256, 0, stream>>>(ln_out, wt_aqkv, aqkv_b, nullptr, qkv_buf, DM, QKVN, XT_QKV);
  cls_part<<<BB*NH*8, 256, 0, stream>>>(qkv_buf, clspart);
  cls_combine<<<BB*NH, 64, 0, stream>>>(clspart, attnout);
  space_attn_mfma<<<BB*NH*FF, 256, 0, stream>>>(qkv_buf, attnout);
  gemm128<2><<<XT_PRJ * YT, 256, 0, stream>>>(attnout, wt_aproj, aproj_b, x, resid_s, DM, DM, XT_PRJ);

  // ---- MLP ----
  ln_k<<<MROWS, 256, 0, stream>>>(resid_s, n2g, n2b, ln_out);
  gemm128<1><<<XT_FC1 * YT, 256, 0, stream>>>(ln_out, wt_fc1, fc1_b, nullptr, h_buf, DM, FCN, XT_FC1);
  gemm128<2><<<XT_PRJ * YT, 256, 0, stream>>>(h_buf, wt_fc2, fc2_b, resid_s, out, FCN, DM, XT_PRJ);
}